// Round 1
// baseline (981.504 us; speedup 1.0000x reference)
//
#include <hip/hip_runtime.h>

#define N_NODES 50000
#define NFEAT   512
#define NHID    128
#define N_EDGES 800000
#define LN_EPS  1e-5f

// ---------------- degree kernel ----------------
__global__ __launch_bounds__(256) void degree_kernel(
    const int* __restrict__ src, const int* __restrict__ dst,
    int* __restrict__ out_deg, int* __restrict__ in_deg)
{
    int i = blockIdx.x * 256 + threadIdx.x;
    if (i < N_EDGES) {
        atomicAdd(&out_deg[src[i]], 1);
        atomicAdd(&in_deg[dst[i]], 1);
    }
}

// ---------------- GEMM: x[n,:] = (h[n,:] * out_norm[n]) @ W ----------------
// block: 256 threads; tile: 64 rows x 128 cols; K-chunk 32
__global__ __launch_bounds__(256) void gemm_kernel(
    const float* __restrict__ h, const float* __restrict__ W,
    const int* __restrict__ out_deg, float* __restrict__ x)
{
    __shared__ float As[64][33];     // +1 pad
    __shared__ float Ws[32][NHID];
    __shared__ float norms[64];

    const int tid  = threadIdx.x;
    const int row0 = blockIdx.x * 64;

    if (tid < 64) {
        int n = row0 + tid;
        float dg = 1.0f;
        if (n < N_NODES) dg = fmaxf((float)out_deg[n], 1.0f);
        norms[tid] = rsqrtf(dg);
    }
    __syncthreads();

    const int tx = tid & 15;     // 16 col-groups of 8
    const int ty = tid >> 4;     // 16 row-groups of 4
    const int c0 = tx * 8;
    const int r0 = ty * 4;

    float acc[4][8];
#pragma unroll
    for (int i = 0; i < 4; i++)
#pragma unroll
        for (int j = 0; j < 8; j++) acc[i][j] = 0.0f;

    const int ar = tid >> 3;          // 0..31 (row within half-tile)
    const int ak = (tid & 7) * 4;     // k offset (float4)

    for (int k0 = 0; k0 < NFEAT; k0 += 32) {
        // stage A (64x32), scaled by out_norm
#pragma unroll
        for (int half = 0; half < 2; half++) {
            int r = ar + half * 32;
            int n = row0 + r;
            float4 v = make_float4(0.f, 0.f, 0.f, 0.f);
            if (n < N_NODES)
                v = *(const float4*)(h + (size_t)n * NFEAT + k0 + ak);
            float nm = norms[r];
            As[r][ak + 0] = v.x * nm;
            As[r][ak + 1] = v.y * nm;
            As[r][ak + 2] = v.z * nm;
            As[r][ak + 3] = v.w * nm;
        }
        // stage W (32x128)
#pragma unroll
        for (int j = 0; j < 4; j++) {
            int i  = tid + j * 256;        // 0..1023 float4 idx
            int kr = i >> 5;               // 0..31
            int cc = (i & 31) * 4;         // 0..124
            *(float4*)&Ws[kr][cc] = *(const float4*)(W + (size_t)(k0 + kr) * NHID + cc);
        }
        __syncthreads();

#pragma unroll
        for (int kk = 0; kk < 32; kk++) {
            float a0 = As[r0 + 0][kk];
            float a1 = As[r0 + 1][kk];
            float a2 = As[r0 + 2][kk];
            float a3 = As[r0 + 3][kk];
            float4 w0 = *(const float4*)&Ws[kk][c0];
            float4 w1 = *(const float4*)&Ws[kk][c0 + 4];
            acc[0][0] += a0 * w0.x; acc[0][1] += a0 * w0.y; acc[0][2] += a0 * w0.z; acc[0][3] += a0 * w0.w;
            acc[0][4] += a0 * w1.x; acc[0][5] += a0 * w1.y; acc[0][6] += a0 * w1.z; acc[0][7] += a0 * w1.w;
            acc[1][0] += a1 * w0.x; acc[1][1] += a1 * w0.y; acc[1][2] += a1 * w0.z; acc[1][3] += a1 * w0.w;
            acc[1][4] += a1 * w1.x; acc[1][5] += a1 * w1.y; acc[1][6] += a1 * w1.z; acc[1][7] += a1 * w1.w;
            acc[2][0] += a2 * w0.x; acc[2][1] += a2 * w0.y; acc[2][2] += a2 * w0.z; acc[2][3] += a2 * w0.w;
            acc[2][4] += a2 * w1.x; acc[2][5] += a2 * w1.y; acc[2][6] += a2 * w1.z; acc[2][7] += a2 * w1.w;
            acc[3][0] += a3 * w0.x; acc[3][1] += a3 * w0.y; acc[3][2] += a3 * w0.z; acc[3][3] += a3 * w0.w;
            acc[3][4] += a3 * w1.x; acc[3][5] += a3 * w1.y; acc[3][6] += a3 * w1.z; acc[3][7] += a3 * w1.w;
        }
        __syncthreads();
    }

#pragma unroll
    for (int i = 0; i < 4; i++) {
        int n = row0 + r0 + i;
        if (n < N_NODES) {
            float4 o0 = make_float4(acc[i][0], acc[i][1], acc[i][2], acc[i][3]);
            float4 o1 = make_float4(acc[i][4], acc[i][5], acc[i][6], acc[i][7]);
            *(float4*)(x + (size_t)n * NHID + c0)     = o0;
            *(float4*)(x + (size_t)n * NHID + c0 + 4) = o1;
        }
    }
}

// ---------------- scatter: agg[dst] += x[src] ----------------
// one wave per edge, 2 floats per lane
__global__ __launch_bounds__(256) void scatter_kernel(
    const int* __restrict__ src, const int* __restrict__ dst,
    const float* __restrict__ x, float* __restrict__ agg)
{
    int e = blockIdx.x * 4 + (threadIdx.x >> 6);
    int lane = threadIdx.x & 63;
    int s = src[e];
    int d = dst[e];
    float2 v = *(const float2*)(x + (size_t)s * NHID + lane * 2);
    atomicAdd(&agg[(size_t)d * NHID + lane * 2 + 0], v.x);
    atomicAdd(&agg[(size_t)d * NHID + lane * 2 + 1], v.y);
}

// ---------------- finalize: v = agg*in_norm + b; LayerNorm(v)*gamma + beta ----------------
__global__ __launch_bounds__(256) void finalize_kernel(
    const float* __restrict__ agg, const int* __restrict__ in_deg,
    const float* __restrict__ b, const float* __restrict__ gamma,
    const float* __restrict__ beta, float* __restrict__ out)
{
    int n = blockIdx.x * 4 + (threadIdx.x >> 6);
    int lane = threadIdx.x & 63;
    float inorm = rsqrtf(fmaxf((float)in_deg[n], 1.0f));
    float2 a = *(const float2*)(agg + (size_t)n * NHID + lane * 2);
    float v0 = a.x * inorm + b[lane * 2 + 0];
    float v1 = a.y * inorm + b[lane * 2 + 1];

    float s = v0 + v1;
#pragma unroll
    for (int off = 32; off > 0; off >>= 1) s += __shfl_down(s, off);
    float mu = __shfl(s, 0) * (1.0f / 128.0f);

    float d0 = v0 - mu, d1 = v1 - mu;
    float q = d0 * d0 + d1 * d1;
#pragma unroll
    for (int off = 32; off > 0; off >>= 1) q += __shfl_down(q, off);
    float var = __shfl(q, 0) * (1.0f / 128.0f);
    float r = rsqrtf(var + LN_EPS);

    out[(size_t)n * NHID + lane * 2 + 0] = d0 * r * gamma[lane * 2 + 0] + beta[lane * 2 + 0];
    out[(size_t)n * NHID + lane * 2 + 1] = d1 * r * gamma[lane * 2 + 1] + beta[lane * 2 + 1];
}

// ---------------- launch ----------------
extern "C" void kernel_launch(void* const* d_in, const int* in_sizes, int n_in,
                              void* d_out, int out_size, void* d_ws, size_t ws_size,
                              hipStream_t stream) {
    const float* h     = (const float*)d_in[0];
    const int*   src   = (const int*)d_in[1];
    const int*   dst   = (const int*)d_in[2];
    const float* W     = (const float*)d_in[3];
    const float* b     = (const float*)d_in[4];
    const float* gamma = (const float*)d_in[5];
    const float* beta  = (const float*)d_in[6];
    float* out = (float*)d_out;

    // workspace layout (256-aligned)
    char* ws = (char*)d_ws;
    const size_t DEG_BYTES = 200704;                 // 50000*4 padded to 256
    int*   in_deg  = (int*)(ws);
    int*   out_deg = (int*)(ws + DEG_BYTES);
    float* agg     = (float*)(ws + 2 * DEG_BYTES);   // 25.6 MB
    float* x       = (float*)(ws + 2 * DEG_BYTES + (size_t)N_NODES * NHID * 4);

    // zero: both deg arrays + agg (contiguous)
    size_t zero_bytes = 2 * DEG_BYTES + (size_t)N_NODES * NHID * 4;
    hipMemsetAsync(d_ws, 0, zero_bytes, stream);

    degree_kernel<<<(N_EDGES + 255) / 256, 256, 0, stream>>>(src, dst, out_deg, in_deg);
    gemm_kernel<<<(N_NODES + 63) / 64, 256, 0, stream>>>(h, W, out_deg, x);
    scatter_kernel<<<N_EDGES / 4, 256, 0, stream>>>(src, dst, x, agg);
    finalize_kernel<<<N_NODES / 4, 256, 0, stream>>>(agg, in_deg, b, gamma, beta, out);
}

// Round 2
// 472.327 us; speedup vs baseline: 2.0780x; 2.0780x over previous
//
#include <hip/hip_runtime.h>

#define N_NODES 50000
#define NFEAT   512
#define NHID    128
#define N_EDGES 800000
#define LN_EPS  1e-5f

// ---------------- degree kernel ----------------
__global__ __launch_bounds__(256) void degree_kernel(
    const int* __restrict__ src, const int* __restrict__ dst,
    int* __restrict__ out_deg, int* __restrict__ in_deg)
{
    int i = blockIdx.x * 256 + threadIdx.x;
    if (i < N_EDGES) {
        atomicAdd(&out_deg[src[i]], 1);
        atomicAdd(&in_deg[dst[i]], 1);
    }
}

// ---------------- exclusive scan of in_deg -> row_ptr (single block) ----------------
__global__ __launch_bounds__(1024) void scan_kernel(
    const int* __restrict__ in_deg, int* __restrict__ row_ptr)
{
    __shared__ int wsum[16];
    __shared__ int carry_s;
    const int tid = threadIdx.x;
    const int lane = tid & 63, wave = tid >> 6;
    if (tid == 0) carry_s = 0;
    __syncthreads();

    for (int base = 0; base < N_NODES; base += 1024) {
        int i = base + tid;
        int v = (i < N_NODES) ? in_deg[i] : 0;
        // inclusive wave scan
        int sv = v;
#pragma unroll
        for (int off = 1; off < 64; off <<= 1) {
            int t = __shfl_up(sv, off);
            if (lane >= off) sv += t;
        }
        if (lane == 63) wsum[wave] = sv;
        __syncthreads();
        if (wave == 0) {
            int wv = (lane < 16) ? wsum[lane] : 0;
#pragma unroll
            for (int off = 1; off < 16; off <<= 1) {
                int t = __shfl_up(wv, off);
                if (lane >= off) wv += t;
            }
            if (lane < 16) wsum[lane] = wv;
        }
        __syncthreads();
        int wave_off = (wave > 0) ? wsum[wave - 1] : 0;
        int excl = carry_s + wave_off + (sv - v);
        if (i < N_NODES) row_ptr[i] = excl;
        __syncthreads();
        if (tid == 0) carry_s += wsum[15];
        __syncthreads();
    }
    if (tid == 0) row_ptr[N_NODES] = carry_s;
}

// ---------------- CSR fill: counting sort of edges by dst ----------------
__global__ __launch_bounds__(256) void fill_kernel(
    const int* __restrict__ src, const int* __restrict__ dst,
    const int* __restrict__ row_ptr, int* __restrict__ cursor,
    int* __restrict__ csr_src)
{
    int e = blockIdx.x * 256 + threadIdx.x;
    if (e < N_EDGES) {
        int d = dst[e];
        int pos = atomicAdd(&cursor[d], 1);
        csr_src[row_ptr[d] + pos] = src[e];
    }
}

// ---------------- GEMM: x[n,:] = (h[n,:] * out_norm[n]) @ W ----------------
__global__ __launch_bounds__(256) void gemm_kernel(
    const float* __restrict__ h, const float* __restrict__ W,
    const int* __restrict__ out_deg, float* __restrict__ x)
{
    __shared__ float As[64][33];
    __shared__ float Ws[32][NHID];
    __shared__ float norms[64];

    const int tid  = threadIdx.x;
    const int row0 = blockIdx.x * 64;

    if (tid < 64) {
        int n = row0 + tid;
        float dg = 1.0f;
        if (n < N_NODES) dg = fmaxf((float)out_deg[n], 1.0f);
        norms[tid] = rsqrtf(dg);
    }
    __syncthreads();

    const int tx = tid & 15;
    const int ty = tid >> 4;
    const int c0 = tx * 8;
    const int r0 = ty * 4;

    float acc[4][8];
#pragma unroll
    for (int i = 0; i < 4; i++)
#pragma unroll
        for (int j = 0; j < 8; j++) acc[i][j] = 0.0f;

    const int ar = tid >> 3;
    const int ak = (tid & 7) * 4;

    for (int k0 = 0; k0 < NFEAT; k0 += 32) {
#pragma unroll
        for (int half = 0; half < 2; half++) {
            int r = ar + half * 32;
            int n = row0 + r;
            float4 v = make_float4(0.f, 0.f, 0.f, 0.f);
            if (n < N_NODES)
                v = *(const float4*)(h + (size_t)n * NFEAT + k0 + ak);
            float nm = norms[r];
            As[r][ak + 0] = v.x * nm;
            As[r][ak + 1] = v.y * nm;
            As[r][ak + 2] = v.z * nm;
            As[r][ak + 3] = v.w * nm;
        }
#pragma unroll
        for (int j = 0; j < 4; j++) {
            int i  = tid + j * 256;
            int kr = i >> 5;
            int cc = (i & 31) * 4;
            *(float4*)&Ws[kr][cc] = *(const float4*)(W + (size_t)(k0 + kr) * NHID + cc);
        }
        __syncthreads();

#pragma unroll
        for (int kk = 0; kk < 32; kk++) {
            float a0 = As[r0 + 0][kk];
            float a1 = As[r0 + 1][kk];
            float a2 = As[r0 + 2][kk];
            float a3 = As[r0 + 3][kk];
            float4 w0 = *(const float4*)&Ws[kk][c0];
            float4 w1 = *(const float4*)&Ws[kk][c0 + 4];
            acc[0][0] += a0 * w0.x; acc[0][1] += a0 * w0.y; acc[0][2] += a0 * w0.z; acc[0][3] += a0 * w0.w;
            acc[0][4] += a0 * w1.x; acc[0][5] += a0 * w1.y; acc[0][6] += a0 * w1.z; acc[0][7] += a0 * w1.w;
            acc[1][0] += a1 * w0.x; acc[1][1] += a1 * w0.y; acc[1][2] += a1 * w0.z; acc[1][3] += a1 * w0.w;
            acc[1][4] += a1 * w1.x; acc[1][5] += a1 * w1.y; acc[1][6] += a1 * w1.z; acc[1][7] += a1 * w1.w;
            acc[2][0] += a2 * w0.x; acc[2][1] += a2 * w0.y; acc[2][2] += a2 * w0.z; acc[2][3] += a2 * w0.w;
            acc[2][4] += a2 * w1.x; acc[2][5] += a2 * w1.y; acc[2][6] += a2 * w1.z; acc[2][7] += a2 * w1.w;
            acc[3][0] += a3 * w0.x; acc[3][1] += a3 * w0.y; acc[3][2] += a3 * w0.z; acc[3][3] += a3 * w0.w;
            acc[3][4] += a3 * w1.x; acc[3][5] += a3 * w1.y; acc[3][6] += a3 * w1.z; acc[3][7] += a3 * w1.w;
        }
        __syncthreads();
    }

#pragma unroll
    for (int i = 0; i < 4; i++) {
        int n = row0 + r0 + i;
        if (n < N_NODES) {
            float4 o0 = make_float4(acc[i][0], acc[i][1], acc[i][2], acc[i][3]);
            float4 o1 = make_float4(acc[i][4], acc[i][5], acc[i][6], acc[i][7]);
            *(float4*)(x + (size_t)n * NHID + c0)     = o0;
            *(float4*)(x + (size_t)n * NHID + c0 + 4) = o1;
        }
    }
}

// ---------------- fused aggregate + in_norm + bias + LayerNorm ----------------
// one wave per node; lane holds feats [2*lane, 2*lane+1]
__global__ __launch_bounds__(256) void aggregate_kernel(
    const float* __restrict__ x, const int* __restrict__ row_ptr,
    const int* __restrict__ csr_src,
    const float* __restrict__ b, const float* __restrict__ gamma,
    const float* __restrict__ beta, float* __restrict__ out)
{
    const int n = blockIdx.x * 4 + (threadIdx.x >> 6);
    const int lane = threadIdx.x & 63;
    const int start = row_ptr[n];
    const int end   = row_ptr[n + 1];

    float ax = 0.0f, ay = 0.0f;
    for (int base = start; base < end; base += 64) {
        int me   = base + lane;
        int msrc = (me < end) ? csr_src[me] : 0;
        int cnt  = min(64, end - base);
        for (int j = 0; j < cnt; ++j) {
            int s = __shfl(msrc, j);
            float2 v = *(const float2*)(x + (size_t)s * NHID + lane * 2);
            ax += v.x;
            ay += v.y;
        }
    }

    float inorm = rsqrtf(fmaxf((float)(end - start), 1.0f));
    float v0 = ax * inorm + b[lane * 2 + 0];
    float v1 = ay * inorm + b[lane * 2 + 1];

    float s = v0 + v1;
#pragma unroll
    for (int off = 32; off > 0; off >>= 1) s += __shfl_down(s, off);
    float mu = __shfl(s, 0) * (1.0f / 128.0f);

    float d0 = v0 - mu, d1 = v1 - mu;
    float q = d0 * d0 + d1 * d1;
#pragma unroll
    for (int off = 32; off > 0; off >>= 1) q += __shfl_down(q, off);
    float var = __shfl(q, 0) * (1.0f / 128.0f);
    float r = rsqrtf(var + LN_EPS);

    out[(size_t)n * NHID + lane * 2 + 0] = d0 * r * gamma[lane * 2 + 0] + beta[lane * 2 + 0];
    out[(size_t)n * NHID + lane * 2 + 1] = d1 * r * gamma[lane * 2 + 1] + beta[lane * 2 + 1];
}

// ---------------- launch ----------------
extern "C" void kernel_launch(void* const* d_in, const int* in_sizes, int n_in,
                              void* d_out, int out_size, void* d_ws, size_t ws_size,
                              hipStream_t stream) {
    const float* h     = (const float*)d_in[0];
    const int*   src   = (const int*)d_in[1];
    const int*   dst   = (const int*)d_in[2];
    const float* W     = (const float*)d_in[3];
    const float* b     = (const float*)d_in[4];
    const float* gamma = (const float*)d_in[5];
    const float* beta  = (const float*)d_in[6];
    float* out = (float*)d_out;

    // workspace layout (256-aligned)
    char* ws = (char*)d_ws;
    const size_t DEG_BYTES = 200704;   // 50000*4 padded
    const size_t RP_BYTES  = 200960;   // 50001*4 padded
    int*   out_deg = (int*)(ws);
    int*   in_deg  = (int*)(ws + DEG_BYTES);
    int*   cursor  = (int*)(ws + 2 * DEG_BYTES);
    int*   row_ptr = (int*)(ws + 3 * DEG_BYTES);
    int*   csr_src = (int*)(ws + 3 * DEG_BYTES + RP_BYTES);
    float* x       = (float*)(ws + 3 * DEG_BYTES + RP_BYTES + (size_t)N_EDGES * 4);

    // zero out_deg + in_deg + cursor (contiguous)
    hipMemsetAsync(d_ws, 0, 3 * DEG_BYTES, stream);

    degree_kernel<<<(N_EDGES + 255) / 256, 256, 0, stream>>>(src, dst, out_deg, in_deg);
    scan_kernel<<<1, 1024, 0, stream>>>(in_deg, row_ptr);
    gemm_kernel<<<(N_NODES + 63) / 64, 256, 0, stream>>>(h, W, out_deg, x);
    fill_kernel<<<(N_EDGES + 255) / 256, 256, 0, stream>>>(src, dst, row_ptr, cursor, csr_src);
    aggregate_kernel<<<N_NODES / 4, 256, 0, stream>>>(x, row_ptr, csr_src, b, gamma, beta, out);
}

// Round 3
// 384.114 us; speedup vs baseline: 2.5552x; 1.2297x over previous
//
#include <hip/hip_runtime.h>

#define N_NODES 50000
#define NFEAT   512
#define NHID    128
#define N_EDGES 800000
#define LN_EPS  1e-5f

typedef __attribute__((ext_vector_type(8))) short bf16x8;
typedef __attribute__((ext_vector_type(4))) float fx4;

__device__ __forceinline__ unsigned short f2bf(float f) {
    union { float f; unsigned u; } v; v.f = f;
    unsigned r = v.u + 0x7FFF + ((v.u >> 16) & 1);   // RNE
    return (unsigned short)(r >> 16);
}

// ---------------- degree kernel ----------------
__global__ __launch_bounds__(256) void degree_kernel(
    const int* __restrict__ src, const int* __restrict__ dst,
    int* __restrict__ out_deg, int* __restrict__ in_deg)
{
    int i = blockIdx.x * 256 + threadIdx.x;
    if (i < N_EDGES) {
        atomicAdd(&out_deg[src[i]], 1);
        atomicAdd(&in_deg[dst[i]], 1);
    }
}

// ---------------- scan phase A: block-local exclusive scan ----------------
__global__ __launch_bounds__(1024) void scan_local(
    const int* __restrict__ in_deg, int* __restrict__ row_ptr, int* __restrict__ bsum)
{
    __shared__ int wsum[16];
    const int tid = threadIdx.x;
    const int lane = tid & 63, wave = tid >> 6;
    int i = blockIdx.x * 1024 + tid;
    int v = (i < N_NODES) ? in_deg[i] : 0;
    int sv = v;
#pragma unroll
    for (int off = 1; off < 64; off <<= 1) {
        int t = __shfl_up(sv, off);
        if (lane >= off) sv += t;
    }
    if (lane == 63) wsum[wave] = sv;
    __syncthreads();
    if (wave == 0) {
        int wv = (lane < 16) ? wsum[lane] : 0;
#pragma unroll
        for (int off = 1; off < 16; off <<= 1) {
            int t = __shfl_up(wv, off);
            if (lane >= off) wv += t;
        }
        if (lane < 16) wsum[lane] = wv;
    }
    __syncthreads();
    int excl = ((wave > 0) ? wsum[wave - 1] : 0) + (sv - v);
    if (i < N_NODES) row_ptr[i] = excl;
    if (tid == 1023) bsum[blockIdx.x] = wsum[15];
}

// ---------------- scan phase B: scan 49 block sums (1 wave) ----------------
__global__ __launch_bounds__(64) void scan_bsums(int* __restrict__ bsum, int* __restrict__ row_ptr)
{
    const int lane = threadIdx.x;
    const int nb = (N_NODES + 1023) / 1024;
    int v = (lane < nb) ? bsum[lane] : 0;
    int sv = v;
#pragma unroll
    for (int off = 1; off < 64; off <<= 1) {
        int t = __shfl_up(sv, off);
        if (lane >= off) sv += t;
    }
    if (lane < nb) bsum[lane] = sv - v;      // exclusive
    if (lane == 63) row_ptr[N_NODES] = sv;   // grand total
}

// ---------------- scan phase C: add block offsets ----------------
__global__ __launch_bounds__(1024) void scan_add(int* __restrict__ row_ptr, const int* __restrict__ bsum)
{
    int i = blockIdx.x * 1024 + threadIdx.x;
    if (i < N_NODES && blockIdx.x > 0) row_ptr[i] += bsum[blockIdx.x];
}

// ---------------- CSR fill ----------------
__global__ __launch_bounds__(256) void fill_kernel(
    const int* __restrict__ src, const int* __restrict__ dst,
    const int* __restrict__ row_ptr, int* __restrict__ cursor,
    int* __restrict__ csr_src)
{
    int e = blockIdx.x * 256 + threadIdx.x;
    if (e < N_EDGES) {
        int d = dst[e];
        int pos = atomicAdd(&cursor[d], 1);
        csr_src[row_ptr[d] + pos] = src[e];
    }
}

// ---------------- W prep: fp32 [512][128] -> bf16 fragment order ----------------
// wf[((kc*8 + t)*64 + lane)*8 + j] = bf16(W[kc*32 + (lane>>4)*8 + j][t*16 + (lane&15)])
__global__ __launch_bounds__(256) void wprep_kernel(
    const float* __restrict__ W, unsigned short* __restrict__ wf)
{
    int tid = blockIdx.x * 256 + threadIdx.x;   // 8192 threads: frag*64 + lane
    int lane = tid & 63;
    int frag = tid >> 6;                        // 0..127 = kc*8 + t
    int kc = frag >> 3, t = frag & 7;
    int n  = t * 16 + (lane & 15);
    int k0 = kc * 32 + (lane >> 4) * 8;
    unsigned short v[8];
#pragma unroll
    for (int j = 0; j < 8; j++)
        v[j] = f2bf(W[(size_t)(k0 + j) * NHID + n]);
    *(bf16x8*)(wf + (size_t)tid * 8) = *(bf16x8*)v;
}

// ---------------- MFMA GEMM: x = (h * out_norm) @ W ----------------
// 256 threads = 4 waves; block covers 64 rows (16 per wave), full 128 cols.
__global__ __launch_bounds__(256) void gemm_mfma(
    const float* __restrict__ h, const unsigned short* __restrict__ wf,
    const int* __restrict__ out_deg, float* __restrict__ x)
{
    const int tid  = threadIdx.x;
    const int wave = tid >> 6;
    const int lane = tid & 63;
    const int m    = lane & 15;
    const int quad = lane >> 4;
    const int row0 = blockIdx.x * 64 + wave * 16;
    const int row  = row0 + m;
    const int rowc = (row < N_NODES) ? row : (N_NODES - 1);

    const float norm = rsqrtf(fmaxf((float)out_deg[rowc], 1.0f));
    const float* hrow = h + (size_t)rowc * NFEAT + quad * 8;

    fx4 acc[8];
#pragma unroll
    for (int t = 0; t < 8; t++) acc[t] = (fx4){0.f, 0.f, 0.f, 0.f};

#pragma unroll 2
    for (int kc = 0; kc < 16; kc++) {
        float4 a0 = *(const float4*)(hrow + kc * 32);
        float4 a1 = *(const float4*)(hrow + kc * 32 + 4);
        unsigned short af[8];
        af[0] = f2bf(a0.x * norm); af[1] = f2bf(a0.y * norm);
        af[2] = f2bf(a0.z * norm); af[3] = f2bf(a0.w * norm);
        af[4] = f2bf(a1.x * norm); af[5] = f2bf(a1.y * norm);
        af[6] = f2bf(a1.z * norm); af[7] = f2bf(a1.w * norm);
        bf16x8 afrag = *(bf16x8*)af;

        const bf16x8* wrow = (const bf16x8*)(wf + ((size_t)kc * 8 * 64 + lane) * 8);
#pragma unroll
        for (int t = 0; t < 8; t++) {
            bf16x8 bfrag = wrow[t * 64];
            acc[t] = __builtin_amdgcn_mfma_f32_16x16x32_bf16(afrag, bfrag, acc[t], 0, 0, 0);
        }
    }

    // C/D layout: col = lane&15, row_in_tile = quad*4 + reg
#pragma unroll
    for (int reg = 0; reg < 4; reg++) {
        int r = row0 + quad * 4 + reg;
        if (r < N_NODES) {
            float* xr = x + (size_t)r * NHID + (lane & 15);
#pragma unroll
            for (int t = 0; t < 8; t++)
                xr[t * 16] = acc[t][reg];
        }
    }
}

// ---------------- fused aggregate + in_norm + bias + LayerNorm ----------------
__global__ __launch_bounds__(256) void aggregate_kernel(
    const float* __restrict__ x, const int* __restrict__ row_ptr,
    const int* __restrict__ csr_src,
    const float* __restrict__ b, const float* __restrict__ gamma,
    const float* __restrict__ beta, float* __restrict__ out)
{
    const int n = blockIdx.x * 4 + (threadIdx.x >> 6);
    const int lane = threadIdx.x & 63;
    const int start = row_ptr[n];
    const int end   = row_ptr[n + 1];

    float ax = 0.0f, ay = 0.0f;
    for (int base = start; base < end; base += 64) {
        int me   = base + lane;
        int msrc = (me < end) ? csr_src[me] : 0;
        int cnt  = min(64, end - base);
        for (int j = 0; j < cnt; ++j) {
            int s = __shfl(msrc, j);
            float2 v = *(const float2*)(x + (size_t)s * NHID + lane * 2);
            ax += v.x;
            ay += v.y;
        }
    }

    float inorm = rsqrtf(fmaxf((float)(end - start), 1.0f));
    float v0 = ax * inorm + b[lane * 2 + 0];
    float v1 = ay * inorm + b[lane * 2 + 1];

    float s = v0 + v1;
#pragma unroll
    for (int off = 32; off > 0; off >>= 1) s += __shfl_down(s, off);
    float mu = __shfl(s, 0) * (1.0f / 128.0f);

    float d0 = v0 - mu, d1 = v1 - mu;
    float q = d0 * d0 + d1 * d1;
#pragma unroll
    for (int off = 32; off > 0; off >>= 1) q += __shfl_down(q, off);
    float var = __shfl(q, 0) * (1.0f / 128.0f);
    float r = rsqrtf(var + LN_EPS);

    out[(size_t)n * NHID + lane * 2 + 0] = d0 * r * gamma[lane * 2 + 0] + beta[lane * 2 + 0];
    out[(size_t)n * NHID + lane * 2 + 1] = d1 * r * gamma[lane * 2 + 1] + beta[lane * 2 + 1];
}

// ---------------- launch ----------------
extern "C" void kernel_launch(void* const* d_in, const int* in_sizes, int n_in,
                              void* d_out, int out_size, void* d_ws, size_t ws_size,
                              hipStream_t stream) {
    const float* h     = (const float*)d_in[0];
    const int*   src   = (const int*)d_in[1];
    const int*   dst   = (const int*)d_in[2];
    const float* W     = (const float*)d_in[3];
    const float* b     = (const float*)d_in[4];
    const float* gamma = (const float*)d_in[5];
    const float* beta  = (const float*)d_in[6];
    float* out = (float*)d_out;

    char* ws = (char*)d_ws;
    const size_t DEG_BYTES = 200704;   // 50000*4 padded
    const size_t RP_BYTES  = 200960;   // 50001*4 padded
    int*            out_deg = (int*)(ws);
    int*            in_deg  = (int*)(ws + DEG_BYTES);
    int*            cursor  = (int*)(ws + 2 * DEG_BYTES);
    int*            row_ptr = (int*)(ws + 3 * DEG_BYTES);
    int*            bsum    = (int*)(ws + 3 * DEG_BYTES + RP_BYTES);
    int*            csr_src = (int*)(ws + 3 * DEG_BYTES + RP_BYTES + 1024);
    unsigned short* wf      = (unsigned short*)(ws + 3 * DEG_BYTES + RP_BYTES + 1024 + (size_t)N_EDGES * 4);
    float*          x       = (float*)(ws + 3 * DEG_BYTES + RP_BYTES + 1024 + (size_t)N_EDGES * 4 + 131072);

    // zero out_deg + in_deg + cursor (contiguous)
    hipMemsetAsync(d_ws, 0, 3 * DEG_BYTES, stream);

    const int NB = (N_NODES + 1023) / 1024;   // 49
    degree_kernel<<<(N_EDGES + 255) / 256, 256, 0, stream>>>(src, dst, out_deg, in_deg);
    scan_local  <<<NB, 1024, 0, stream>>>(in_deg, row_ptr, bsum);
    scan_bsums  <<<1, 64, 0, stream>>>(bsum, row_ptr);
    scan_add    <<<NB, 1024, 0, stream>>>(row_ptr, bsum);
    wprep_kernel<<<32, 256, 0, stream>>>(W, wf);
    fill_kernel <<<(N_EDGES + 255) / 256, 256, 0, stream>>>(src, dst, row_ptr, cursor, csr_src);
    gemm_mfma   <<<(N_NODES + 63) / 64, 256, 0, stream>>>(h, wf, out_deg, x);
    aggregate_kernel<<<N_NODES / 4, 256, 0, stream>>>(x, row_ptr, csr_src, b, gamma, beta, out);
}

// Round 4
// 353.332 us; speedup vs baseline: 2.7778x; 1.0871x over previous
//
#include <hip/hip_runtime.h>

#define N_NODES 50000
#define NFEAT   512
#define NHID    128
#define N_EDGES 800000
#define LN_EPS  1e-5f

typedef __attribute__((ext_vector_type(8))) short bf16x8;
typedef __attribute__((ext_vector_type(4))) float fx4;

__device__ __forceinline__ unsigned short f2bf(float f) {
    union { float f; unsigned u; } v; v.f = f;
    unsigned r = v.u + 0x7FFF + ((v.u >> 16) & 1);   // RNE
    return (unsigned short)(r >> 16);
}

// ---------------- degree kernel ----------------
__global__ __launch_bounds__(256) void degree_kernel(
    const int* __restrict__ src, const int* __restrict__ dst,
    int* __restrict__ out_deg, int* __restrict__ in_deg)
{
    int i = blockIdx.x * 256 + threadIdx.x;
    if (i < N_EDGES) {
        atomicAdd(&out_deg[src[i]], 1);
        atomicAdd(&in_deg[dst[i]], 1);
    }
}

// ---------------- scan phase A: block-local exclusive scan ----------------
__global__ __launch_bounds__(1024) void scan_local(
    const int* __restrict__ in_deg, int* __restrict__ row_ptr, int* __restrict__ bsum)
{
    __shared__ int wsum[16];
    const int tid = threadIdx.x;
    const int lane = tid & 63, wave = tid >> 6;
    int i = blockIdx.x * 1024 + tid;
    int v = (i < N_NODES) ? in_deg[i] : 0;
    int sv = v;
#pragma unroll
    for (int off = 1; off < 64; off <<= 1) {
        int t = __shfl_up(sv, off);
        if (lane >= off) sv += t;
    }
    if (lane == 63) wsum[wave] = sv;
    __syncthreads();
    if (wave == 0) {
        int wv = (lane < 16) ? wsum[lane] : 0;
#pragma unroll
        for (int off = 1; off < 16; off <<= 1) {
            int t = __shfl_up(wv, off);
            if (lane >= off) wv += t;
        }
        if (lane < 16) wsum[lane] = wv;
    }
    __syncthreads();
    int excl = ((wave > 0) ? wsum[wave - 1] : 0) + (sv - v);
    if (i < N_NODES) row_ptr[i] = excl;
    if (tid == 1023) bsum[blockIdx.x] = wsum[15];
}

// ---------------- scan phase B: scan block sums (1 wave) ----------------
__global__ __launch_bounds__(64) void scan_bsums(int* __restrict__ bsum, int* __restrict__ row_ptr)
{
    const int lane = threadIdx.x;
    const int nb = (N_NODES + 1023) / 1024;
    int v = (lane < nb) ? bsum[lane] : 0;
    int sv = v;
#pragma unroll
    for (int off = 1; off < 64; off <<= 1) {
        int t = __shfl_up(sv, off);
        if (lane >= off) sv += t;
    }
    if (lane < nb) bsum[lane] = sv - v;
    if (lane == 63) row_ptr[N_NODES] = sv;
}

// ---------------- scan phase C: add block offsets ----------------
__global__ __launch_bounds__(1024) void scan_add(int* __restrict__ row_ptr, const int* __restrict__ bsum)
{
    int i = blockIdx.x * 1024 + threadIdx.x;
    if (i < N_NODES && blockIdx.x > 0) row_ptr[i] += bsum[blockIdx.x];
}

// ---------------- CSR fill ----------------
__global__ __launch_bounds__(256) void fill_kernel(
    const int* __restrict__ src, const int* __restrict__ dst,
    const int* __restrict__ row_ptr, int* __restrict__ cursor,
    int* __restrict__ csr_src)
{
    int e = blockIdx.x * 256 + threadIdx.x;
    if (e < N_EDGES) {
        int d = dst[e];
        int pos = atomicAdd(&cursor[d], 1);
        csr_src[row_ptr[d] + pos] = src[e];
    }
}

// ---------------- W prep: fp32 [512][128] -> bf16 fragment order ----------------
// wf[((kc*8 + t)*64 + lane)*8 + j] = bf16(W[kc*32 + (lane>>4)*8 + j][t*16 + (lane&15)])
__global__ __launch_bounds__(256) void wprep_kernel(
    const float* __restrict__ W, unsigned short* __restrict__ wf)
{
    int tid = blockIdx.x * 256 + threadIdx.x;   // 8192 threads: frag*64 + lane
    int lane = tid & 63;
    int frag = tid >> 6;                        // 0..127 = kc*8 + t
    int kc = frag >> 3, t = frag & 7;
    int n  = t * 16 + (lane & 15);
    int k0 = kc * 32 + (lane >> 4) * 8;
    unsigned short v[8];
#pragma unroll
    for (int j = 0; j < 8; j++)
        v[j] = f2bf(W[(size_t)(k0 + j) * NHID + n]);
    *(bf16x8*)(wf + (size_t)tid * 8) = *(bf16x8*)v;
}

// ---------------- MFMA GEMM: x = (h @ W) * out_norm (norm in epilogue) ----------------
// block = 256 threads (4 waves), 16 rows; waves share A-frags in LDS, split 8 col tiles 2 each.
__global__ __launch_bounds__(256) void gemm_mfma(
    const float* __restrict__ h, const unsigned short* __restrict__ wf,
    const int* __restrict__ out_deg, float* __restrict__ x)
{
    __shared__ unsigned short afrag_lds[16 * 64 * 8];   // [kc][lane][8] bf16, 16 KB
    __shared__ float norms_lds[16];

    const int tid  = threadIdx.x;
    const int row0 = blockIdx.x * 16;

    if (tid < 16)
        norms_lds[tid] = rsqrtf(fmaxf((float)out_deg[row0 + tid], 1.0f));

    // ---- stage 16 rows of h -> bf16 A-fragments in LDS ----
    const float4* hbase = (const float4*)(h + (size_t)row0 * NFEAT);
#pragma unroll
    for (int it = 0; it < 8; it++) {
        int i = tid + it * 256;            // float4 index, 0..2047
        float4 v = hbase[i];
        int r  = i >> 7;                   // row 0..15
        int k0 = (i & 127) << 2;           // k offset 0..508
        int kc = k0 >> 5;
        int q  = (k0 >> 3) & 3;
        int j  = k0 & 7;                   // 0 or 4
        unsigned long long pk =
            (unsigned long long)f2bf(v.x)
          | ((unsigned long long)f2bf(v.y) << 16)
          | ((unsigned long long)f2bf(v.z) << 32)
          | ((unsigned long long)f2bf(v.w) << 48);
        *(unsigned long long*)(afrag_lds + kc * 512 + (q * 16 + r) * 8 + j) = pk;
    }
    __syncthreads();

    // ---- MFMA: each wave does col tiles t0, t0+1 ----
    const int wave = tid >> 6;
    const int lane = tid & 63;
    const int t0   = wave * 2;

    fx4 acc0 = (fx4){0.f, 0.f, 0.f, 0.f};
    fx4 acc1 = (fx4){0.f, 0.f, 0.f, 0.f};

    const bf16x8* afp = (const bf16x8*)afrag_lds + lane;           // + kc*64
    const bf16x8* wfp = (const bf16x8*)wf + t0 * 64 + lane;        // + kc*512 (+64 for t0+1)

#pragma unroll 4
    for (int kc = 0; kc < 16; kc++) {
        bf16x8 a  = afp[kc * 64];
        bf16x8 b0 = wfp[kc * 512];
        bf16x8 b1 = wfp[kc * 512 + 64];
        acc0 = __builtin_amdgcn_mfma_f32_16x16x32_bf16(a, b0, acc0, 0, 0, 0);
        acc1 = __builtin_amdgcn_mfma_f32_16x16x32_bf16(a, b1, acc1, 0, 0, 0);
    }

    // ---- epilogue: scale rows by out_norm, store ----
    const int q = lane >> 4;
    const int c = lane & 15;
#pragma unroll
    for (int reg = 0; reg < 4; reg++) {
        int r = row0 + q * 4 + reg;
        float nm = norms_lds[q * 4 + reg];
        float* xr = x + (size_t)r * NHID;
        xr[t0 * 16 + c]       = acc0[reg] * nm;
        xr[(t0 + 1) * 16 + c] = acc1[reg] * nm;
    }
}

// ---------------- fused aggregate + in_norm + bias + LayerNorm ----------------
__global__ __launch_bounds__(256) void aggregate_kernel(
    const float* __restrict__ x, const int* __restrict__ row_ptr,
    const int* __restrict__ csr_src,
    const float* __restrict__ b, const float* __restrict__ gamma,
    const float* __restrict__ beta, float* __restrict__ out)
{
    const int n = blockIdx.x * 4 + (threadIdx.x >> 6);
    const int lane = threadIdx.x & 63;
    const int start = row_ptr[n];
    const int end   = row_ptr[n + 1];

    float ax = 0.0f, ay = 0.0f;
    for (int base = start; base < end; base += 64) {
        int me   = base + lane;
        int msrc = (me < end) ? csr_src[me] : 0;
        int cnt  = min(64, end - base);
        int j = 0;
        for (; j + 4 <= cnt; j += 4) {
            int s0 = __shfl(msrc, j);
            int s1 = __shfl(msrc, j + 1);
            int s2 = __shfl(msrc, j + 2);
            int s3 = __shfl(msrc, j + 3);
            float2 v0 = *(const float2*)(x + (size_t)s0 * NHID + lane * 2);
            float2 v1 = *(const float2*)(x + (size_t)s1 * NHID + lane * 2);
            float2 v2 = *(const float2*)(x + (size_t)s2 * NHID + lane * 2);
            float2 v3 = *(const float2*)(x + (size_t)s3 * NHID + lane * 2);
            ax += v0.x + v1.x + v2.x + v3.x;
            ay += v0.y + v1.y + v2.y + v3.y;
        }
        for (; j < cnt; ++j) {
            int s = __shfl(msrc, j);
            float2 v = *(const float2*)(x + (size_t)s * NHID + lane * 2);
            ax += v.x;
            ay += v.y;
        }
    }

    float inorm = rsqrtf(fmaxf((float)(end - start), 1.0f));
    float v0 = ax * inorm + b[lane * 2 + 0];
    float v1 = ay * inorm + b[lane * 2 + 1];

    float s = v0 + v1;
#pragma unroll
    for (int off = 32; off > 0; off >>= 1) s += __shfl_down(s, off);
    float mu = __shfl(s, 0) * (1.0f / 128.0f);

    float d0 = v0 - mu, d1 = v1 - mu;
    float q = d0 * d0 + d1 * d1;
#pragma unroll
    for (int off = 32; off > 0; off >>= 1) q += __shfl_down(q, off);
    float var = __shfl(q, 0) * (1.0f / 128.0f);
    float r = rsqrtf(var + LN_EPS);

    out[(size_t)n * NHID + lane * 2 + 0] = d0 * r * gamma[lane * 2 + 0] + beta[lane * 2 + 0];
    out[(size_t)n * NHID + lane * 2 + 1] = d1 * r * gamma[lane * 2 + 1] + beta[lane * 2 + 1];
}

// ---------------- launch ----------------
extern "C" void kernel_launch(void* const* d_in, const int* in_sizes, int n_in,
                              void* d_out, int out_size, void* d_ws, size_t ws_size,
                              hipStream_t stream) {
    const float* h     = (const float*)d_in[0];
    const int*   src   = (const int*)d_in[1];
    const int*   dst   = (const int*)d_in[2];
    const float* W     = (const float*)d_in[3];
    const float* b     = (const float*)d_in[4];
    const float* gamma = (const float*)d_in[5];
    const float* beta  = (const float*)d_in[6];
    float* out = (float*)d_out;

    char* ws = (char*)d_ws;
    const size_t DEG_BYTES = 200704;   // 50000*4 padded
    const size_t RP_BYTES  = 200960;   // 50001*4 padded
    int*            out_deg = (int*)(ws);
    int*            in_deg  = (int*)(ws + DEG_BYTES);
    int*            cursor  = (int*)(ws + 2 * DEG_BYTES);
    int*            row_ptr = (int*)(ws + 3 * DEG_BYTES);
    int*            bsum    = (int*)(ws + 3 * DEG_BYTES + RP_BYTES);
    int*            csr_src = (int*)(ws + 3 * DEG_BYTES + RP_BYTES + 1024);
    unsigned short* wf      = (unsigned short*)(ws + 3 * DEG_BYTES + RP_BYTES + 1024 + (size_t)N_EDGES * 4);
    float*          x       = (float*)(ws + 3 * DEG_BYTES + RP_BYTES + 1024 + (size_t)N_EDGES * 4 + 131072);

    // zero out_deg + in_deg + cursor (contiguous)
    hipMemsetAsync(d_ws, 0, 3 * DEG_BYTES, stream);

    const int NB = (N_NODES + 1023) / 1024;   // 49
    degree_kernel<<<(N_EDGES + 255) / 256, 256, 0, stream>>>(src, dst, out_deg, in_deg);
    scan_local  <<<NB, 1024, 0, stream>>>(in_deg, row_ptr, bsum);
    scan_bsums  <<<1, 64, 0, stream>>>(bsum, row_ptr);
    scan_add    <<<NB, 1024, 0, stream>>>(row_ptr, bsum);
    wprep_kernel<<<32, 256, 0, stream>>>(W, wf);
    fill_kernel <<<(N_EDGES + 255) / 256, 256, 0, stream>>>(src, dst, row_ptr, cursor, csr_src);
    gemm_mfma   <<<N_NODES / 16, 256, 0, stream>>>(h, wf, out_deg, x);
    aggregate_kernel<<<N_NODES / 4, 256, 0, stream>>>(x, row_ptr, csr_src, b, gamma, beta, out);
}

// Round 5
// 325.227 us; speedup vs baseline: 3.0179x; 1.0864x over previous
//
#include <hip/hip_runtime.h>

#define N_NODES 50000
#define NFEAT   512
#define NHID    128
#define N_EDGES 800000
#define LN_EPS  1e-5f

typedef __attribute__((ext_vector_type(8))) short bf16x8;
typedef __attribute__((ext_vector_type(4))) float fx4;

__device__ __forceinline__ unsigned short f2bf(float f) {
    union { float f; unsigned u; } v; v.f = f;
    unsigned r = v.u + 0x7FFF + ((v.u >> 16) & 1);   // RNE
    return (unsigned short)(r >> 16);
}

// ---------------- degree + slot assignment: 4 edges/thread ----------------
// pos = atomicAdd(in_deg[dst]) doubles as the CSR slot for this edge.
__global__ __launch_bounds__(256) void degree_kernel(
    const int* __restrict__ src, const int* __restrict__ dst,
    int* __restrict__ out_deg, int* __restrict__ in_deg,
    int* __restrict__ edge_pos)
{
    int i = blockIdx.x * 256 + threadIdx.x;     // 0..199999
    if (i >= N_EDGES / 4) return;
    int4 s4 = ((const int4*)src)[i];
    int4 d4 = ((const int4*)dst)[i];
    int4 p;
    p.x = atomicAdd(&in_deg[d4.x], 1);
    p.y = atomicAdd(&in_deg[d4.y], 1);
    p.z = atomicAdd(&in_deg[d4.z], 1);
    p.w = atomicAdd(&in_deg[d4.w], 1);
    atomicAdd(&out_deg[s4.x], 1);
    atomicAdd(&out_deg[s4.y], 1);
    atomicAdd(&out_deg[s4.z], 1);
    atomicAdd(&out_deg[s4.w], 1);
    ((int4*)edge_pos)[i] = p;
}

// ---------------- scan phase A: block-local exclusive scan ----------------
__global__ __launch_bounds__(1024) void scan_local(
    const int* __restrict__ in_deg, int* __restrict__ row_ptr, int* __restrict__ bsum)
{
    __shared__ int wsum[16];
    const int tid = threadIdx.x;
    const int lane = tid & 63, wave = tid >> 6;
    int i = blockIdx.x * 1024 + tid;
    int v = (i < N_NODES) ? in_deg[i] : 0;
    int sv = v;
#pragma unroll
    for (int off = 1; off < 64; off <<= 1) {
        int t = __shfl_up(sv, off);
        if (lane >= off) sv += t;
    }
    if (lane == 63) wsum[wave] = sv;
    __syncthreads();
    if (wave == 0) {
        int wv = (lane < 16) ? wsum[lane] : 0;
#pragma unroll
        for (int off = 1; off < 16; off <<= 1) {
            int t = __shfl_up(wv, off);
            if (lane >= off) wv += t;
        }
        if (lane < 16) wsum[lane] = wv;
    }
    __syncthreads();
    int excl = ((wave > 0) ? wsum[wave - 1] : 0) + (sv - v);
    if (i < N_NODES) row_ptr[i] = excl;
    if (tid == 1023) bsum[blockIdx.x] = wsum[15];
}

// ---------------- scan phase B ----------------
__global__ __launch_bounds__(64) void scan_bsums(int* __restrict__ bsum, int* __restrict__ row_ptr)
{
    const int lane = threadIdx.x;
    const int nb = (N_NODES + 1023) / 1024;
    int v = (lane < nb) ? bsum[lane] : 0;
    int sv = v;
#pragma unroll
    for (int off = 1; off < 64; off <<= 1) {
        int t = __shfl_up(sv, off);
        if (lane >= off) sv += t;
    }
    if (lane < nb) bsum[lane] = sv - v;
    if (lane == 63) row_ptr[N_NODES] = sv;
}

// ---------------- scan phase C ----------------
__global__ __launch_bounds__(1024) void scan_add(int* __restrict__ row_ptr, const int* __restrict__ bsum)
{
    int i = blockIdx.x * 1024 + threadIdx.x;
    if (i < N_NODES && blockIdx.x > 0) row_ptr[i] += bsum[blockIdx.x];
}

// ---------------- CSR fill (atomic-free) ----------------
__global__ __launch_bounds__(256) void fill_kernel(
    const int* __restrict__ src, const int* __restrict__ dst,
    const int* __restrict__ row_ptr, const int* __restrict__ edge_pos,
    int* __restrict__ csr_src)
{
    int e = blockIdx.x * 256 + threadIdx.x;
    if (e < N_EDGES) {
        int d = dst[e];
        csr_src[row_ptr[d] + edge_pos[e]] = src[e];
    }
}

// ---------------- W prep: fp32 [512][128] -> bf16 fragment order ----------------
__global__ __launch_bounds__(256) void wprep_kernel(
    const float* __restrict__ W, unsigned short* __restrict__ wf)
{
    int tid = blockIdx.x * 256 + threadIdx.x;
    int lane = tid & 63;
    int frag = tid >> 6;                        // 0..127 = kc*8 + t
    int kc = frag >> 3, t = frag & 7;
    int n  = t * 16 + (lane & 15);
    int k0 = kc * 32 + (lane >> 4) * 8;
    unsigned short v[8];
#pragma unroll
    for (int j = 0; j < 8; j++)
        v[j] = f2bf(W[(size_t)(k0 + j) * NHID + n]);
    *(bf16x8*)(wf + (size_t)tid * 8) = *(bf16x8*)v;
}

// ---------------- MFMA GEMM: x = (h @ W) * out_norm (norm in epilogue) ----------------
__global__ __launch_bounds__(256) void gemm_mfma(
    const float* __restrict__ h, const unsigned short* __restrict__ wf,
    const int* __restrict__ out_deg, float* __restrict__ x)
{
    __shared__ unsigned short afrag_lds[16 * 64 * 8];   // 16 KB
    __shared__ float norms_lds[16];

    const int tid  = threadIdx.x;
    const int row0 = blockIdx.x * 16;

    if (tid < 16)
        norms_lds[tid] = rsqrtf(fmaxf((float)out_deg[row0 + tid], 1.0f));

    const float4* hbase = (const float4*)(h + (size_t)row0 * NFEAT);
#pragma unroll
    for (int it = 0; it < 8; it++) {
        int i = tid + it * 256;
        float4 v = hbase[i];
        int r  = i >> 7;
        int k0 = (i & 127) << 2;
        int kc = k0 >> 5;
        int q  = (k0 >> 3) & 3;
        int j  = k0 & 7;
        unsigned long long pk =
            (unsigned long long)f2bf(v.x)
          | ((unsigned long long)f2bf(v.y) << 16)
          | ((unsigned long long)f2bf(v.z) << 32)
          | ((unsigned long long)f2bf(v.w) << 48);
        *(unsigned long long*)(afrag_lds + kc * 512 + (q * 16 + r) * 8 + j) = pk;
    }
    __syncthreads();

    const int wave = tid >> 6;
    const int lane = tid & 63;
    const int t0   = wave * 2;

    fx4 acc0 = (fx4){0.f, 0.f, 0.f, 0.f};
    fx4 acc1 = (fx4){0.f, 0.f, 0.f, 0.f};

    const bf16x8* afp = (const bf16x8*)afrag_lds + lane;
    const bf16x8* wfp = (const bf16x8*)wf + t0 * 64 + lane;

#pragma unroll 4
    for (int kc = 0; kc < 16; kc++) {
        bf16x8 a  = afp[kc * 64];
        bf16x8 b0 = wfp[kc * 512];
        bf16x8 b1 = wfp[kc * 512 + 64];
        acc0 = __builtin_amdgcn_mfma_f32_16x16x32_bf16(a, b0, acc0, 0, 0, 0);
        acc1 = __builtin_amdgcn_mfma_f32_16x16x32_bf16(a, b1, acc1, 0, 0, 0);
    }

    const int q = lane >> 4;
    const int c = lane & 15;
#pragma unroll
    for (int reg = 0; reg < 4; reg++) {
        int r = row0 + q * 4 + reg;
        float nm = norms_lds[q * 4 + reg];
        float* xr = x + (size_t)r * NHID;
        xr[t0 * 16 + c]       = acc0[reg] * nm;
        xr[(t0 + 1) * 16 + c] = acc1[reg] * nm;
    }
}

// ---------------- fused aggregate + in_norm + bias + LayerNorm ----------------
// one wave per node; half-waves process alternating edges; lane covers 4 feats.
__global__ __launch_bounds__(256) void aggregate_kernel(
    const float* __restrict__ x, const int* __restrict__ row_ptr,
    const int* __restrict__ csr_src,
    const float* __restrict__ b, const float* __restrict__ gamma,
    const float* __restrict__ beta, float* __restrict__ out)
{
    const int n    = blockIdx.x * 4 + (threadIdx.x >> 6);
    const int lane = threadIdx.x & 63;
    const int half = lane >> 5;
    const int c    = lane & 31;          // feat group: 4c..4c+3
    const int start = row_ptr[n];
    const int end   = row_ptr[n + 1];

    float a0 = 0.f, a1 = 0.f, a2 = 0.f, a3 = 0.f;

    for (int base = start; base < end; base += 64) {
        int me   = base + lane;
        int msrc = (me < end) ? csr_src[me] : 0;
        int cnt  = min(64, end - base);
        int npair = (cnt + 1) >> 1;
        int j = 0;
        for (; j + 4 <= npair; j += 4) {
            int i0 = 2 * j + half, i1 = i0 + 2, i2 = i0 + 4, i3 = i0 + 6;
            int s0 = __shfl(msrc, i0);
            int s1 = __shfl(msrc, i1);
            int s2 = __shfl(msrc, i2);
            int s3 = __shfl(msrc, i3);
            float m0 = (i0 < cnt) ? 1.f : 0.f;
            float m1 = (i1 < cnt) ? 1.f : 0.f;
            float m2 = (i2 < cnt) ? 1.f : 0.f;
            float m3 = (i3 < cnt) ? 1.f : 0.f;
            float4 v0 = *(const float4*)(x + (size_t)s0 * NHID + c * 4);
            float4 v1 = *(const float4*)(x + (size_t)s1 * NHID + c * 4);
            float4 v2 = *(const float4*)(x + (size_t)s2 * NHID + c * 4);
            float4 v3 = *(const float4*)(x + (size_t)s3 * NHID + c * 4);
            a0 += v0.x * m0 + v1.x * m1 + v2.x * m2 + v3.x * m3;
            a1 += v0.y * m0 + v1.y * m1 + v2.y * m2 + v3.y * m3;
            a2 += v0.z * m0 + v1.z * m1 + v2.z * m2 + v3.z * m3;
            a3 += v0.w * m0 + v1.w * m1 + v2.w * m2 + v3.w * m3;
        }
        for (; j < npair; ++j) {
            int i0 = 2 * j + half;
            int s0 = __shfl(msrc, i0);
            float m0 = (i0 < cnt) ? 1.f : 0.f;
            float4 v0 = *(const float4*)(x + (size_t)s0 * NHID + c * 4);
            a0 += v0.x * m0;
            a1 += v0.y * m0;
            a2 += v0.z * m0;
            a3 += v0.w * m0;
        }
    }

    // combine halves (partner lane holds same feats over the other edge subset)
    a0 += __shfl_xor(a0, 32);
    a1 += __shfl_xor(a1, 32);
    a2 += __shfl_xor(a2, 32);
    a3 += __shfl_xor(a3, 32);

    float inorm = rsqrtf(fmaxf((float)(end - start), 1.0f));
    float4 bb = *(const float4*)(b + c * 4);
    float v0 = a0 * inorm + bb.x;
    float v1 = a1 * inorm + bb.y;
    float v2 = a2 * inorm + bb.z;
    float v3 = a3 * inorm + bb.w;

    float s = v0 + v1 + v2 + v3;
#pragma unroll
    for (int off = 16; off > 0; off >>= 1) s += __shfl_xor(s, off);
    float mu = s * (1.0f / 128.0f);

    float d0 = v0 - mu, d1 = v1 - mu, d2 = v2 - mu, d3 = v3 - mu;
    float qd = d0 * d0 + d1 * d1 + d2 * d2 + d3 * d3;
#pragma unroll
    for (int off = 16; off > 0; off >>= 1) qd += __shfl_xor(qd, off);
    float var = qd * (1.0f / 128.0f);
    float rs = rsqrtf(var + LN_EPS);

    if (half == 0) {
        float4 gg = *(const float4*)(gamma + c * 4);
        float4 be = *(const float4*)(beta + c * 4);
        float4 o;
        o.x = d0 * rs * gg.x + be.x;
        o.y = d1 * rs * gg.y + be.y;
        o.z = d2 * rs * gg.z + be.z;
        o.w = d3 * rs * gg.w + be.w;
        *(float4*)(out + (size_t)n * NHID + c * 4) = o;
    }
}

// ---------------- launch ----------------
extern "C" void kernel_launch(void* const* d_in, const int* in_sizes, int n_in,
                              void* d_out, int out_size, void* d_ws, size_t ws_size,
                              hipStream_t stream) {
    const float* h     = (const float*)d_in[0];
    const int*   src   = (const int*)d_in[1];
    const int*   dst   = (const int*)d_in[2];
    const float* W     = (const float*)d_in[3];
    const float* b     = (const float*)d_in[4];
    const float* gamma = (const float*)d_in[5];
    const float* beta  = (const float*)d_in[6];
    float* out = (float*)d_out;

    char* ws = (char*)d_ws;
    const size_t DEG_BYTES = 200704;   // 50000*4 padded
    const size_t RP_BYTES  = 200960;   // 50001*4 padded
    int*            out_deg  = (int*)(ws);
    int*            in_deg   = (int*)(ws + DEG_BYTES);
    int*            row_ptr  = (int*)(ws + 2 * DEG_BYTES);
    int*            bsum     = (int*)(ws + 2 * DEG_BYTES + RP_BYTES);
    int*            edge_pos = (int*)(ws + 2 * DEG_BYTES + RP_BYTES + 1024);
    int*            csr_src  = (int*)(ws + 2 * DEG_BYTES + RP_BYTES + 1024 + (size_t)N_EDGES * 4);
    unsigned short* wf       = (unsigned short*)(ws + 2 * DEG_BYTES + RP_BYTES + 1024 + 2 * (size_t)N_EDGES * 4);
    float*          x        = (float*)(ws + 2 * DEG_BYTES + RP_BYTES + 1024 + 2 * (size_t)N_EDGES * 4 + 131072);

    // zero out_deg + in_deg (contiguous)
    hipMemsetAsync(d_ws, 0, 2 * DEG_BYTES, stream);

    const int NB = (N_NODES + 1023) / 1024;   // 49
    degree_kernel<<<(N_EDGES / 4 + 255) / 256, 256, 0, stream>>>(src, dst, out_deg, in_deg, edge_pos);
    scan_local  <<<NB, 1024, 0, stream>>>(in_deg, row_ptr, bsum);
    scan_bsums  <<<1, 64, 0, stream>>>(bsum, row_ptr);
    scan_add    <<<NB, 1024, 0, stream>>>(row_ptr, bsum);
    wprep_kernel<<<32, 256, 0, stream>>>(W, wf);
    fill_kernel <<<(N_EDGES + 255) / 256, 256, 0, stream>>>(src, dst, row_ptr, edge_pos, csr_src);
    gemm_mfma   <<<N_NODES / 16, 256, 0, stream>>>(h, wf, out_deg, x);
    aggregate_kernel<<<N_NODES / 4, 256, 0, stream>>>(x, row_ptr, csr_src, b, gamma, beta, out);
}

// Round 6
// 299.881 us; speedup vs baseline: 3.2730x; 1.0845x over previous
//
#include <hip/hip_runtime.h>

#define N_NODES 50000
#define NFEAT   512
#define NHID    128
#define N_EDGES 800000
#define LN_EPS  1e-5f

#define GEMM_BLOCKS 3125   // N_NODES / 16
#define DEG_BLOCKS  3125   // N_EDGES / 256

typedef __attribute__((ext_vector_type(8))) short bf16x8;
typedef __attribute__((ext_vector_type(4))) float fx4;

__device__ __forceinline__ unsigned short f2bf(float f) {
    union { float f; unsigned u; } v; v.f = f;
    unsigned r = v.u + 0x7FFF + ((v.u >> 16) & 1);   // RNE
    return (unsigned short)(r >> 16);
}

// ---------------- W prep: fp32 [512][128] -> bf16 fragment order ----------------
__global__ __launch_bounds__(256) void wprep_kernel(
    const float* __restrict__ W, unsigned short* __restrict__ wf)
{
    int tid = blockIdx.x * 256 + threadIdx.x;
    int lane = tid & 63;
    int frag = tid >> 6;                        // 0..127 = kc*8 + t
    int kc = frag >> 3, t = frag & 7;
    int n  = t * 16 + (lane & 15);
    int k0 = kc * 32 + (lane >> 4) * 8;
    unsigned short v[8];
#pragma unroll
    for (int j = 0; j < 8; j++)
        v[j] = f2bf(W[(size_t)(k0 + j) * NHID + n]);
    *(bf16x8*)(wf + (size_t)tid * 8) = *(bf16x8*)v;
}

// ---------------- fused: GEMM (even blocks) + degree/slot (odd blocks) ----------------
// GEMM writes x_unnorm = h @ W (out_norm applied later in aggregate).
// Degree part is atomic-latency-bound with idle VALU/MFMA; GEMM hides under it.
__global__ __launch_bounds__(256) void fused_gemm_degree(
    const float* __restrict__ h, const unsigned short* __restrict__ wf,
    float* __restrict__ x,
    const int* __restrict__ src, const int* __restrict__ dst,
    int* __restrict__ out_deg, int* __restrict__ in_deg,
    int* __restrict__ edge_pos)
{
    __shared__ unsigned short afrag_lds[16 * 64 * 8];   // 16 KB

    const int tid = threadIdx.x;

    if (blockIdx.x & 1) {
        // ---- degree + CSR slot assignment: 1 edge/thread ----
        int e = (blockIdx.x >> 1) * 256 + tid;
        int s = src[e];
        int d = dst[e];
        int pos = atomicAdd(&in_deg[d], 1);
        atomicAdd(&out_deg[s], 1);
        edge_pos[e] = pos;
        return;
    }

    // ---- GEMM: 16 rows per block ----
    const int row0 = (blockIdx.x >> 1) * 16;

    const float4* hbase = (const float4*)(h + (size_t)row0 * NFEAT);
#pragma unroll
    for (int it = 0; it < 8; it++) {
        int i = tid + it * 256;
        float4 v = hbase[i];
        int r  = i >> 7;
        int k0 = (i & 127) << 2;
        int kc = k0 >> 5;
        int q  = (k0 >> 3) & 3;
        int j  = k0 & 7;
        unsigned long long pk =
            (unsigned long long)f2bf(v.x)
          | ((unsigned long long)f2bf(v.y) << 16)
          | ((unsigned long long)f2bf(v.z) << 32)
          | ((unsigned long long)f2bf(v.w) << 48);
        *(unsigned long long*)(afrag_lds + kc * 512 + (q * 16 + r) * 8 + j) = pk;
    }
    __syncthreads();

    const int wave = tid >> 6;
    const int lane = tid & 63;
    const int t0   = wave * 2;

    fx4 acc0 = (fx4){0.f, 0.f, 0.f, 0.f};
    fx4 acc1 = (fx4){0.f, 0.f, 0.f, 0.f};

    const bf16x8* afp = (const bf16x8*)afrag_lds + lane;
    const bf16x8* wfp = (const bf16x8*)wf + t0 * 64 + lane;

#pragma unroll 4
    for (int kc = 0; kc < 16; kc++) {
        bf16x8 a  = afp[kc * 64];
        bf16x8 b0 = wfp[kc * 512];
        bf16x8 b1 = wfp[kc * 512 + 64];
        acc0 = __builtin_amdgcn_mfma_f32_16x16x32_bf16(a, b0, acc0, 0, 0, 0);
        acc1 = __builtin_amdgcn_mfma_f32_16x16x32_bf16(a, b1, acc1, 0, 0, 0);
    }

    const int q = lane >> 4;
    const int c = lane & 15;
#pragma unroll
    for (int reg = 0; reg < 4; reg++) {
        int r = row0 + q * 4 + reg;
        float* xr = x + (size_t)r * NHID;
        xr[t0 * 16 + c]       = acc0[reg];
        xr[(t0 + 1) * 16 + c] = acc1[reg];
    }
}

// ---------------- scan phase A: block-local exclusive scan ----------------
__global__ __launch_bounds__(1024) void scan_local(
    const int* __restrict__ in_deg, int* __restrict__ row_ptr, int* __restrict__ bsum)
{
    __shared__ int wsum[16];
    const int tid = threadIdx.x;
    const int lane = tid & 63, wave = tid >> 6;
    int i = blockIdx.x * 1024 + tid;
    int v = (i < N_NODES) ? in_deg[i] : 0;
    int sv = v;
#pragma unroll
    for (int off = 1; off < 64; off <<= 1) {
        int t = __shfl_up(sv, off);
        if (lane >= off) sv += t;
    }
    if (lane == 63) wsum[wave] = sv;
    __syncthreads();
    if (wave == 0) {
        int wv = (lane < 16) ? wsum[lane] : 0;
#pragma unroll
        for (int off = 1; off < 16; off <<= 1) {
            int t = __shfl_up(wv, off);
            if (lane >= off) wv += t;
        }
        if (lane < 16) wsum[lane] = wv;
    }
    __syncthreads();
    int excl = ((wave > 0) ? wsum[wave - 1] : 0) + (sv - v);
    if (i < N_NODES) row_ptr[i] = excl;
    if (tid == 1023) bsum[blockIdx.x] = wsum[15];
}

// ---------------- scan phase B ----------------
__global__ __launch_bounds__(64) void scan_bsums(int* __restrict__ bsum, int* __restrict__ row_ptr)
{
    const int lane = threadIdx.x;
    const int nb = (N_NODES + 1023) / 1024;
    int v = (lane < nb) ? bsum[lane] : 0;
    int sv = v;
#pragma unroll
    for (int off = 1; off < 64; off <<= 1) {
        int t = __shfl_up(sv, off);
        if (lane >= off) sv += t;
    }
    if (lane < nb) bsum[lane] = sv - v;
    if (lane == 63) row_ptr[N_NODES] = sv;
}

// ---------------- scan phase C: block offsets + out_norm ----------------
__global__ __launch_bounds__(1024) void scan_add(
    int* __restrict__ row_ptr, const int* __restrict__ bsum,
    const int* __restrict__ out_deg, float* __restrict__ out_norm)
{
    int i = blockIdx.x * 1024 + threadIdx.x;
    if (i < N_NODES) {
        if (blockIdx.x > 0) row_ptr[i] += bsum[blockIdx.x];
        out_norm[i] = rsqrtf(fmaxf((float)out_deg[i], 1.0f));
    }
}

// ---------------- CSR fill (atomic-free) ----------------
__global__ __launch_bounds__(256) void fill_kernel(
    const int* __restrict__ src, const int* __restrict__ dst,
    const int* __restrict__ row_ptr, const int* __restrict__ edge_pos,
    int* __restrict__ csr_src)
{
    int e = blockIdx.x * 256 + threadIdx.x;
    if (e < N_EDGES) {
        int d = dst[e];
        csr_src[row_ptr[d] + edge_pos[e]] = src[e];
    }
}

// ---------------- fused aggregate + norms + bias + LayerNorm ----------------
// one wave per node; half-waves process alternating edges; lane covers 4 feats.
// gathers x_unnorm[s] * out_norm[s].
__global__ __launch_bounds__(256) void aggregate_kernel(
    const float* __restrict__ x, const int* __restrict__ row_ptr,
    const int* __restrict__ csr_src, const float* __restrict__ out_norm,
    const float* __restrict__ b, const float* __restrict__ gamma,
    const float* __restrict__ beta, float* __restrict__ out)
{
    const int n    = blockIdx.x * 4 + (threadIdx.x >> 6);
    const int lane = threadIdx.x & 63;
    const int half = lane >> 5;
    const int c    = lane & 31;          // feat group: 4c..4c+3
    const int start = row_ptr[n];
    const int end   = row_ptr[n + 1];

    float a0 = 0.f, a1 = 0.f, a2 = 0.f, a3 = 0.f;

    for (int base = start; base < end; base += 64) {
        int me   = base + lane;
        int msrc = (me < end) ? csr_src[me] : 0;
        int cnt  = min(64, end - base);
        int npair = (cnt + 1) >> 1;
        int j = 0;
        for (; j + 4 <= npair; j += 4) {
            int i0 = 2 * j + half, i1 = i0 + 2, i2 = i0 + 4, i3 = i0 + 6;
            int s0 = __shfl(msrc, i0);
            int s1 = __shfl(msrc, i1);
            int s2 = __shfl(msrc, i2);
            int s3 = __shfl(msrc, i3);
            float w0 = (i0 < cnt) ? out_norm[s0] : 0.f;
            float w1 = (i1 < cnt) ? out_norm[s1] : 0.f;
            float w2 = (i2 < cnt) ? out_norm[s2] : 0.f;
            float w3 = (i3 < cnt) ? out_norm[s3] : 0.f;
            float4 v0 = *(const float4*)(x + (size_t)s0 * NHID + c * 4);
            float4 v1 = *(const float4*)(x + (size_t)s1 * NHID + c * 4);
            float4 v2 = *(const float4*)(x + (size_t)s2 * NHID + c * 4);
            float4 v3 = *(const float4*)(x + (size_t)s3 * NHID + c * 4);
            a0 += v0.x * w0 + v1.x * w1 + v2.x * w2 + v3.x * w3;
            a1 += v0.y * w0 + v1.y * w1 + v2.y * w2 + v3.y * w3;
            a2 += v0.z * w0 + v1.z * w1 + v2.z * w2 + v3.z * w3;
            a3 += v0.w * w0 + v1.w * w1 + v2.w * w2 + v3.w * w3;
        }
        for (; j < npair; ++j) {
            int i0 = 2 * j + half;
            int s0 = __shfl(msrc, i0);
            float w0 = (i0 < cnt) ? out_norm[s0] : 0.f;
            float4 v0 = *(const float4*)(x + (size_t)s0 * NHID + c * 4);
            a0 += v0.x * w0;
            a1 += v0.y * w0;
            a2 += v0.z * w0;
            a3 += v0.w * w0;
        }
    }

    // combine halves
    a0 += __shfl_xor(a0, 32);
    a1 += __shfl_xor(a1, 32);
    a2 += __shfl_xor(a2, 32);
    a3 += __shfl_xor(a3, 32);

    float inorm = rsqrtf(fmaxf((float)(end - start), 1.0f));
    float4 bb = *(const float4*)(b + c * 4);
    float v0 = a0 * inorm + bb.x;
    float v1 = a1 * inorm + bb.y;
    float v2 = a2 * inorm + bb.z;
    float v3 = a3 * inorm + bb.w;

    float s = v0 + v1 + v2 + v3;
#pragma unroll
    for (int off = 16; off > 0; off >>= 1) s += __shfl_xor(s, off);
    float mu = s * (1.0f / 128.0f);

    float d0 = v0 - mu, d1 = v1 - mu, d2 = v2 - mu, d3 = v3 - mu;
    float qd = d0 * d0 + d1 * d1 + d2 * d2 + d3 * d3;
#pragma unroll
    for (int off = 16; off > 0; off >>= 1) qd += __shfl_xor(qd, off);
    float var = qd * (1.0f / 128.0f);
    float rs = rsqrtf(var + LN_EPS);

    if (half == 0) {
        float4 gg = *(const float4*)(gamma + c * 4);
        float4 be = *(const float4*)(beta + c * 4);
        float4 o;
        o.x = d0 * rs * gg.x + be.x;
        o.y = d1 * rs * gg.y + be.y;
        o.z = d2 * rs * gg.z + be.z;
        o.w = d3 * rs * gg.w + be.w;
        *(float4*)(out + (size_t)n * NHID + c * 4) = o;
    }
}

// ---------------- launch ----------------
extern "C" void kernel_launch(void* const* d_in, const int* in_sizes, int n_in,
                              void* d_out, int out_size, void* d_ws, size_t ws_size,
                              hipStream_t stream) {
    const float* h     = (const float*)d_in[0];
    const int*   src   = (const int*)d_in[1];
    const int*   dst   = (const int*)d_in[2];
    const float* W     = (const float*)d_in[3];
    const float* b     = (const float*)d_in[4];
    const float* gamma = (const float*)d_in[5];
    const float* beta  = (const float*)d_in[6];
    float* out = (float*)d_out;

    char* ws = (char*)d_ws;
    const size_t DEG_BYTES = 200704;   // 50000*4 padded
    const size_t RP_BYTES  = 200960;   // 50001*4 padded
    int*            out_deg  = (int*)(ws);
    int*            in_deg   = (int*)(ws + DEG_BYTES);
    int*            row_ptr  = (int*)(ws + 2 * DEG_BYTES);
    float*          out_norm = (float*)(ws + 2 * DEG_BYTES + RP_BYTES);
    int*            bsum     = (int*)(ws + 3 * DEG_BYTES + RP_BYTES);
    int*            edge_pos = (int*)(ws + 3 * DEG_BYTES + RP_BYTES + 1024);
    int*            csr_src  = (int*)(ws + 3 * DEG_BYTES + RP_BYTES + 1024 + (size_t)N_EDGES * 4);
    unsigned short* wf       = (unsigned short*)(ws + 3 * DEG_BYTES + RP_BYTES + 1024 + 2 * (size_t)N_EDGES * 4);
    float*          x        = (float*)(ws + 3 * DEG_BYTES + RP_BYTES + 1024 + 2 * (size_t)N_EDGES * 4 + 131072);

    // zero out_deg + in_deg (contiguous)
    hipMemsetAsync(d_ws, 0, 2 * DEG_BYTES, stream);

    const int NB = (N_NODES + 1023) / 1024;   // 49
    wprep_kernel<<<32, 256, 0, stream>>>(W, wf);
    fused_gemm_degree<<<GEMM_BLOCKS + DEG_BLOCKS, 256, 0, stream>>>(
        h, wf, x, src, dst, out_deg, in_deg, edge_pos);
    scan_local  <<<NB, 1024, 0, stream>>>(in_deg, row_ptr, bsum);
    scan_bsums  <<<1, 64, 0, stream>>>(bsum, row_ptr);
    scan_add    <<<NB, 1024, 0, stream>>>(row_ptr, bsum, out_deg, out_norm);
    fill_kernel <<<(N_EDGES + 255) / 256, 256, 0, stream>>>(src, dst, row_ptr, edge_pos, csr_src);
    aggregate_kernel<<<N_NODES / 4, 256, 0, stream>>>(
        x, row_ptr, csr_src, out_norm, b, gamma, beta, out);
}

// Round 7
// 257.218 us; speedup vs baseline: 3.8158x; 1.1659x over previous
//
#include <hip/hip_runtime.h>

#define N_NODES 50000
#define NFEAT   512
#define NHID    128
#define N_EDGES 800000
#define LN_EPS  1e-5f

#define GEMM_ROWS   32
#define GEMM_BLOCKS ((N_NODES + GEMM_ROWS - 1) / GEMM_ROWS)   // 1563
#define DEG_BLOCKS  (N_EDGES / 256)                           // 3125

typedef __attribute__((ext_vector_type(8))) short bf16x8;
typedef __attribute__((ext_vector_type(4))) float fx4;

__device__ __forceinline__ unsigned short f2bf(float f) {
    union { float f; unsigned u; } v; v.f = f;
    unsigned r = v.u + 0x7FFF + ((v.u >> 16) & 1);   // RNE
    return (unsigned short)(r >> 16);
}

// unpack 2 bf16 packed in a uint -> 2 floats (bf16 = top half of fp32)
__device__ __forceinline__ void bf2x(unsigned u, float& lo, float& hi) {
    union { unsigned u; float f; } a, b;
    a.u = u << 16;
    b.u = u & 0xFFFF0000u;
    lo = a.f; hi = b.f;
}

// ---------------- W prep: fp32 [512][128] -> bf16 fragment order ----------------
__global__ __launch_bounds__(256) void wprep_kernel(
    const float* __restrict__ W, unsigned short* __restrict__ wf)
{
    int tid = blockIdx.x * 256 + threadIdx.x;
    int lane = tid & 63;
    int frag = tid >> 6;                        // 0..127 = kc*8 + t
    int kc = frag >> 3, t = frag & 7;
    int n  = t * 16 + (lane & 15);
    int k0 = kc * 32 + (lane >> 4) * 8;
    unsigned short v[8];
#pragma unroll
    for (int j = 0; j < 8; j++)
        v[j] = f2bf(W[(size_t)(k0 + j) * NHID + n]);
    *(bf16x8*)(wf + (size_t)tid * 8) = *(bf16x8*)v;
}

// ---------------- fused: GEMM (even blocks of first span) + degree (rest) ----------------
// GEMM writes x_bf16 = bf16(h @ W); out_norm applied later in aggregate.
__global__ __launch_bounds__(256) void fused_gemm_degree(
    const float* __restrict__ h, const unsigned short* __restrict__ wf,
    unsigned short* __restrict__ x,
    const int* __restrict__ src, const int* __restrict__ dst,
    int* __restrict__ out_deg, int* __restrict__ in_deg,
    int* __restrict__ edge_pos)
{
    __shared__ unsigned short afrag_lds[2][16 * 64 * 8];   // 32 KB

    const int tid = threadIdx.x;
    const int B = blockIdx.x;
    bool isDeg; int id;
    if (B < 2 * GEMM_BLOCKS) { isDeg = (B & 1); id = B >> 1; }
    else                     { isDeg = true;    id = B - GEMM_BLOCKS; }

    if (isDeg) {
        // ---- degree + CSR slot assignment: 1 edge/thread ----
        int e = id * 256 + tid;
        int s = src[e];
        int d = dst[e];
        int pos = atomicAdd(&in_deg[d], 1);
        atomicAdd(&out_deg[s], 1);
        edge_pos[e] = pos;
        return;
    }

    // ---- GEMM: 32 rows per block ----
    const int row0 = id * GEMM_ROWS;

#pragma unroll
    for (int it = 0; it < 16; it++) {
        int i = tid + it * 256;            // float4 index, 0..4095
        int r  = i >> 7;                   // row 0..31
        int grow = row0 + r;
        if (grow > N_NODES - 1) grow = N_NODES - 1;
        float4 v = ((const float4*)h)[(size_t)grow * 128 + (i & 127)];
        int g  = r >> 4;
        int rr = r & 15;
        int k0 = (i & 127) << 2;
        int kc = k0 >> 5;
        int q  = (k0 >> 3) & 3;
        int j  = k0 & 7;
        unsigned long long pk =
            (unsigned long long)f2bf(v.x)
          | ((unsigned long long)f2bf(v.y) << 16)
          | ((unsigned long long)f2bf(v.z) << 32)
          | ((unsigned long long)f2bf(v.w) << 48);
        *(unsigned long long*)(&afrag_lds[g][0] + kc * 512 + (q * 16 + rr) * 8 + j) = pk;
    }
    __syncthreads();

    const int wave = tid >> 6;
    const int lane = tid & 63;
    const int t0   = wave * 2;

    fx4 acc00 = (fx4){0.f, 0.f, 0.f, 0.f};
    fx4 acc01 = (fx4){0.f, 0.f, 0.f, 0.f};
    fx4 acc10 = (fx4){0.f, 0.f, 0.f, 0.f};
    fx4 acc11 = (fx4){0.f, 0.f, 0.f, 0.f};

    const bf16x8* a0p = (const bf16x8*)&afrag_lds[0][0] + lane;
    const bf16x8* a1p = (const bf16x8*)&afrag_lds[1][0] + lane;
    const bf16x8* wfp = (const bf16x8*)wf + t0 * 64 + lane;

#pragma unroll 4
    for (int kc = 0; kc < 16; kc++) {
        bf16x8 a0 = a0p[kc * 64];
        bf16x8 a1 = a1p[kc * 64];
        bf16x8 b0 = wfp[kc * 512];
        bf16x8 b1 = wfp[kc * 512 + 64];
        acc00 = __builtin_amdgcn_mfma_f32_16x16x32_bf16(a0, b0, acc00, 0, 0, 0);
        acc01 = __builtin_amdgcn_mfma_f32_16x16x32_bf16(a0, b1, acc01, 0, 0, 0);
        acc10 = __builtin_amdgcn_mfma_f32_16x16x32_bf16(a1, b0, acc10, 0, 0, 0);
        acc11 = __builtin_amdgcn_mfma_f32_16x16x32_bf16(a1, b1, acc11, 0, 0, 0);
    }

    const int q = lane >> 4;
    const int c = lane & 15;
#pragma unroll
    for (int reg = 0; reg < 4; reg++) {
        int r0 = row0 + q * 4 + reg;
        if (r0 < N_NODES) {
            unsigned short* xr = x + (size_t)r0 * NHID;
            xr[t0 * 16 + c]       = f2bf(acc00[reg]);
            xr[(t0 + 1) * 16 + c] = f2bf(acc01[reg]);
        }
        int r1 = row0 + 16 + q * 4 + reg;
        if (r1 < N_NODES) {
            unsigned short* xr = x + (size_t)r1 * NHID;
            xr[t0 * 16 + c]       = f2bf(acc10[reg]);
            xr[(t0 + 1) * 16 + c] = f2bf(acc11[reg]);
        }
    }
}

// ---------------- scan phase A: block-local exclusive scan ----------------
__global__ __launch_bounds__(1024) void scan_local(
    const int* __restrict__ in_deg, int* __restrict__ row_ptr, int* __restrict__ bsum)
{
    __shared__ int wsum[16];
    const int tid = threadIdx.x;
    const int lane = tid & 63, wave = tid >> 6;
    int i = blockIdx.x * 1024 + tid;
    int v = (i < N_NODES) ? in_deg[i] : 0;
    int sv = v;
#pragma unroll
    for (int off = 1; off < 64; off <<= 1) {
        int t = __shfl_up(sv, off);
        if (lane >= off) sv += t;
    }
    if (lane == 63) wsum[wave] = sv;
    __syncthreads();
    if (wave == 0) {
        int wv = (lane < 16) ? wsum[lane] : 0;
#pragma unroll
        for (int off = 1; off < 16; off <<= 1) {
            int t = __shfl_up(wv, off);
            if (lane >= off) wv += t;
        }
        if (lane < 16) wsum[lane] = wv;
    }
    __syncthreads();
    int excl = ((wave > 0) ? wsum[wave - 1] : 0) + (sv - v);
    if (i < N_NODES) row_ptr[i] = excl;
    if (tid == 1023) bsum[blockIdx.x] = wsum[15];
}

// ---------------- scan phase B ----------------
__global__ __launch_bounds__(64) void scan_bsums(int* __restrict__ bsum, int* __restrict__ row_ptr)
{
    const int lane = threadIdx.x;
    const int nb = (N_NODES + 1023) / 1024;
    int v = (lane < nb) ? bsum[lane] : 0;
    int sv = v;
#pragma unroll
    for (int off = 1; off < 64; off <<= 1) {
        int t = __shfl_up(sv, off);
        if (lane >= off) sv += t;
    }
    if (lane < nb) bsum[lane] = sv - v;
    if (lane == 63) row_ptr[N_NODES] = sv;
}

// ---------------- scan phase C: block offsets + out_norm ----------------
__global__ __launch_bounds__(1024) void scan_add(
    int* __restrict__ row_ptr, const int* __restrict__ bsum,
    const int* __restrict__ out_deg, float* __restrict__ out_norm)
{
    int i = blockIdx.x * 1024 + threadIdx.x;
    if (i < N_NODES) {
        if (blockIdx.x > 0) row_ptr[i] += bsum[blockIdx.x];
        out_norm[i] = rsqrtf(fmaxf((float)out_deg[i], 1.0f));
    }
}

// ---------------- CSR fill (atomic-free) ----------------
__global__ __launch_bounds__(256) void fill_kernel(
    const int* __restrict__ src, const int* __restrict__ dst,
    const int* __restrict__ row_ptr, const int* __restrict__ edge_pos,
    int* __restrict__ csr_src)
{
    int e = blockIdx.x * 256 + threadIdx.x;
    if (e < N_EDGES) {
        int d = dst[e];
        csr_src[row_ptr[d] + edge_pos[e]] = src[e];
    }
}

// ---------------- fused aggregate + norms + bias + LayerNorm ----------------
// one wave per node; half-waves process alternating edges; lane covers 4 feats (bf16).
__global__ __launch_bounds__(256) void aggregate_kernel(
    const unsigned short* __restrict__ x, const int* __restrict__ row_ptr,
    const int* __restrict__ csr_src, const float* __restrict__ out_norm,
    const float* __restrict__ b, const float* __restrict__ gamma,
    const float* __restrict__ beta, float* __restrict__ out)
{
    const int n    = blockIdx.x * 4 + (threadIdx.x >> 6);
    const int lane = threadIdx.x & 63;
    const int half = lane >> 5;
    const int c    = lane & 31;          // feat group: 4c..4c+3
    const int start = row_ptr[n];
    const int end   = row_ptr[n + 1];

    float a0 = 0.f, a1 = 0.f, a2 = 0.f, a3 = 0.f;

    for (int base = start; base < end; base += 64) {
        int me   = base + lane;
        int msrc = (me < end) ? csr_src[me] : 0;
        int cnt  = min(64, end - base);
        int npair = (cnt + 1) >> 1;
        int j = 0;
        for (; j + 4 <= npair; j += 4) {
            int i0 = 2 * j + half, i1 = i0 + 2, i2 = i0 + 4, i3 = i0 + 6;
            int s0 = __shfl(msrc, i0);
            int s1 = __shfl(msrc, i1);
            int s2 = __shfl(msrc, i2);
            int s3 = __shfl(msrc, i3);
            float w0 = (i0 < cnt) ? out_norm[s0] : 0.f;
            float w1 = (i1 < cnt) ? out_norm[s1] : 0.f;
            float w2 = (i2 < cnt) ? out_norm[s2] : 0.f;
            float w3 = (i3 < cnt) ? out_norm[s3] : 0.f;
            uint2 u0 = *(const uint2*)(x + (size_t)s0 * NHID + c * 4);
            uint2 u1 = *(const uint2*)(x + (size_t)s1 * NHID + c * 4);
            uint2 u2 = *(const uint2*)(x + (size_t)s2 * NHID + c * 4);
            uint2 u3 = *(const uint2*)(x + (size_t)s3 * NHID + c * 4);
            float p0, p1, p2, p3;
            bf2x(u0.x, p0, p1); bf2x(u0.y, p2, p3);
            a0 += p0 * w0; a1 += p1 * w0; a2 += p2 * w0; a3 += p3 * w0;
            bf2x(u1.x, p0, p1); bf2x(u1.y, p2, p3);
            a0 += p0 * w1; a1 += p1 * w1; a2 += p2 * w1; a3 += p3 * w1;
            bf2x(u2.x, p0, p1); bf2x(u2.y, p2, p3);
            a0 += p0 * w2; a1 += p1 * w2; a2 += p2 * w2; a3 += p3 * w2;
            bf2x(u3.x, p0, p1); bf2x(u3.y, p2, p3);
            a0 += p0 * w3; a1 += p1 * w3; a2 += p2 * w3; a3 += p3 * w3;
        }
        for (; j < npair; ++j) {
            int i0 = 2 * j + half;
            int s0 = __shfl(msrc, i0);
            float w0 = (i0 < cnt) ? out_norm[s0] : 0.f;
            uint2 u0 = *(const uint2*)(x + (size_t)s0 * NHID + c * 4);
            float p0, p1, p2, p3;
            bf2x(u0.x, p0, p1); bf2x(u0.y, p2, p3);
            a0 += p0 * w0; a1 += p1 * w0; a2 += p2 * w0; a3 += p3 * w0;
        }
    }

    // combine halves
    a0 += __shfl_xor(a0, 32);
    a1 += __shfl_xor(a1, 32);
    a2 += __shfl_xor(a2, 32);
    a3 += __shfl_xor(a3, 32);

    float inorm = rsqrtf(fmaxf((float)(end - start), 1.0f));
    float4 bb = *(const float4*)(b + c * 4);
    float v0 = a0 * inorm + bb.x;
    float v1 = a1 * inorm + bb.y;
    float v2 = a2 * inorm + bb.z;
    float v3 = a3 * inorm + bb.w;

    float s = v0 + v1 + v2 + v3;
#pragma unroll
    for (int off = 16; off > 0; off >>= 1) s += __shfl_xor(s, off);
    float mu = s * (1.0f / 128.0f);

    float d0 = v0 - mu, d1 = v1 - mu, d2 = v2 - mu, d3 = v3 - mu;
    float qd = d0 * d0 + d1 * d1 + d2 * d2 + d3 * d3;
#pragma unroll
    for (int off = 16; off > 0; off >>= 1) qd += __shfl_xor(qd, off);
    float var = qd * (1.0f / 128.0f);
    float rs = rsqrtf(var + LN_EPS);

    if (half == 0) {
        float4 gg = *(const float4*)(gamma + c * 4);
        float4 be = *(const float4*)(beta + c * 4);
        float4 o;
        o.x = d0 * rs * gg.x + be.x;
        o.y = d1 * rs * gg.y + be.y;
        o.z = d2 * rs * gg.z + be.z;
        o.w = d3 * rs * gg.w + be.w;
        *(float4*)(out + (size_t)n * NHID + c * 4) = o;
    }
}

// ---------------- launch ----------------
extern "C" void kernel_launch(void* const* d_in, const int* in_sizes, int n_in,
                              void* d_out, int out_size, void* d_ws, size_t ws_size,
                              hipStream_t stream) {
    const float* h     = (const float*)d_in[0];
    const int*   src   = (const int*)d_in[1];
    const int*   dst   = (const int*)d_in[2];
    const float* W     = (const float*)d_in[3];
    const float* b     = (const float*)d_in[4];
    const float* gamma = (const float*)d_in[5];
    const float* beta  = (const float*)d_in[6];
    float* out = (float*)d_out;

    char* ws = (char*)d_ws;
    const size_t DEG_BYTES = 200704;   // 50000*4 padded
    const size_t RP_BYTES  = 200960;   // 50001*4 padded
    int*            out_deg  = (int*)(ws);
    int*            in_deg   = (int*)(ws + DEG_BYTES);
    int*            row_ptr  = (int*)(ws + 2 * DEG_BYTES);
    float*          out_norm = (float*)(ws + 2 * DEG_BYTES + RP_BYTES);
    int*            bsum     = (int*)(ws + 3 * DEG_BYTES + RP_BYTES);
    int*            edge_pos = (int*)(ws + 3 * DEG_BYTES + RP_BYTES + 1024);
    int*            csr_src  = (int*)(ws + 3 * DEG_BYTES + RP_BYTES + 1024 + (size_t)N_EDGES * 4);
    unsigned short* wf       = (unsigned short*)(ws + 3 * DEG_BYTES + RP_BYTES + 1024 + 2 * (size_t)N_EDGES * 4);
    unsigned short* x        = (unsigned short*)(ws + 3 * DEG_BYTES + RP_BYTES + 1024 + 2 * (size_t)N_EDGES * 4 + 131072);

    // zero out_deg + in_deg (contiguous)
    hipMemsetAsync(d_ws, 0, 2 * DEG_BYTES, stream);

    const int NB = (N_NODES + 1023) / 1024;   // 49
    wprep_kernel<<<32, 256, 0, stream>>>(W, wf);
    fused_gemm_degree<<<GEMM_BLOCKS + DEG_BLOCKS, 256, 0, stream>>>(
        h, wf, x, src, dst, out_deg, in_deg, edge_pos);
    scan_local  <<<NB, 1024, 0, stream>>>(in_deg, row_ptr, bsum);
    scan_bsums  <<<1, 64, 0, stream>>>(bsum, row_ptr);
    scan_add    <<<NB, 1024, 0, stream>>>(row_ptr, bsum, out_deg, out_norm);
    fill_kernel <<<(N_EDGES + 255) / 256, 256, 0, stream>>>(src, dst, row_ptr, edge_pos, csr_src);
    aggregate_kernel<<<N_NODES / 4, 256, 0, stream>>>(
        x, row_ptr, csr_src, out_norm, b, gamma, beta, out);
}

// Round 8
// 255.397 us; speedup vs baseline: 3.8431x; 1.0071x over previous
//
#include <hip/hip_runtime.h>

#define N_NODES 50000
#define NFEAT   512
#define NHID    128
#define N_EDGES 800000
#define LN_EPS  1e-5f

#define GEMM_ROWS   32
#define GEMM_BLOCKS ((N_NODES + GEMM_ROWS - 1) / GEMM_ROWS)   // 1563
#define DEG_BLOCKS  (N_EDGES / 256)                           // 3125
#define NB_SCAN     ((N_NODES + 1023) / 1024)                 // 49

typedef __attribute__((ext_vector_type(8))) short bf16x8;
typedef __attribute__((ext_vector_type(4))) float fx4;

__device__ __forceinline__ unsigned short f2bf(float f) {
    union { float f; unsigned u; } v; v.f = f;
    unsigned r = v.u + 0x7FFF + ((v.u >> 16) & 1);   // RNE
    return (unsigned short)(r >> 16);
}

// unpack 2 bf16 packed in a uint -> 2 floats (bf16 = top half of fp32)
__device__ __forceinline__ void bf2x(unsigned u, float& lo, float& hi) {
    union { unsigned u; float f; } a, b;
    a.u = u << 16;
    b.u = u & 0xFFFF0000u;
    lo = a.f; hi = b.f;
}

// ---------------- prep: zero degree arrays + W -> bf16 fragment order ----------------
// grid 64x256. All threads zero 2*DEG_BYTES; blocks 0..31 also transpose W.
__global__ __launch_bounds__(256) void prep_kernel(
    const float* __restrict__ W, unsigned short* __restrict__ wf,
    int4* __restrict__ zero_ptr)
{
    int t = blockIdx.x * 256 + threadIdx.x;      // 0..16383
#pragma unroll
    for (int i = t; i < 25088; i += 16384)       // 2*200704/16
        zero_ptr[i] = make_int4(0, 0, 0, 0);

    if (blockIdx.x < 32) {
        int lane = t & 63;
        int frag = t >> 6;                       // 0..127 = kc*8 + tt
        int kc = frag >> 3, tt = frag & 7;
        int n  = tt * 16 + (lane & 15);
        int k0 = kc * 32 + (lane >> 4) * 8;
        unsigned short v[8];
#pragma unroll
        for (int j = 0; j < 8; j++)
            v[j] = f2bf(W[(size_t)(k0 + j) * NHID + n]);
        *(bf16x8*)(wf + (size_t)t * 8) = *(bf16x8*)v;
    }
}

// ---------------- fused: GEMM (even blocks of first span) + degree (rest) ----------------
// GEMM writes x_bf16 = bf16(h @ W); out_norm applied later in aggregate.
// LDS granules XOR-swizzled: G' = q*16 + (rr ^ (q | ((kc&1)<<2))) -> 2-way max on writes.
__global__ __launch_bounds__(256) void fused_gemm_degree(
    const float* __restrict__ h, const unsigned short* __restrict__ wf,
    unsigned short* __restrict__ x,
    const int* __restrict__ src, const int* __restrict__ dst,
    int* __restrict__ out_deg, int* __restrict__ in_deg,
    int* __restrict__ edge_pos)
{
    __shared__ unsigned short afrag_lds[2][16 * 64 * 8];   // 32 KB

    const int tid = threadIdx.x;
    const int B = blockIdx.x;
    bool isDeg; int id;
    if (B < 2 * GEMM_BLOCKS) { isDeg = (B & 1); id = B >> 1; }
    else                     { isDeg = true;    id = B - GEMM_BLOCKS; }

    if (isDeg) {
        int e = id * 256 + tid;
        int s = src[e];
        int d = dst[e];
        int pos = atomicAdd(&in_deg[d], 1);
        atomicAdd(&out_deg[s], 1);
        edge_pos[e] = pos;
        return;
    }

    // ---- GEMM: 32 rows per block ----
    const int row0 = id * GEMM_ROWS;

#pragma unroll
    for (int it = 0; it < 16; it++) {
        int i = tid + it * 256;            // float4 index, 0..4095
        int r  = i >> 7;                   // row 0..31
        int grow = row0 + r;
        if (grow > N_NODES - 1) grow = N_NODES - 1;
        float4 v = ((const float4*)h)[(size_t)grow * 128 + (i & 127)];
        int g  = r >> 4;
        int rr = r & 15;
        int k0 = (i & 127) << 2;
        int kc = k0 >> 5;
        int q  = (k0 >> 3) & 3;
        int j  = k0 & 7;
        int gp = q * 16 + (rr ^ (q | ((kc & 1) << 2)));   // swizzled granule
        unsigned long long pk =
            (unsigned long long)f2bf(v.x)
          | ((unsigned long long)f2bf(v.y) << 16)
          | ((unsigned long long)f2bf(v.z) << 32)
          | ((unsigned long long)f2bf(v.w) << 48);
        *(unsigned long long*)(&afrag_lds[g][0] + kc * 512 + gp * 8 + j) = pk;
    }
    __syncthreads();

    const int wave = tid >> 6;
    const int lane = tid & 63;
    const int t0   = wave * 2;
    const int rr_l = lane & 15;
    const int q_l  = lane >> 4;
    const int g_e  = q_l * 16 + (rr_l ^ q_l);        // even kc granule
    const int g_o  = q_l * 16 + (rr_l ^ q_l ^ 4);    // odd kc granule

    fx4 acc00 = (fx4){0.f, 0.f, 0.f, 0.f};
    fx4 acc01 = (fx4){0.f, 0.f, 0.f, 0.f};
    fx4 acc10 = (fx4){0.f, 0.f, 0.f, 0.f};
    fx4 acc11 = (fx4){0.f, 0.f, 0.f, 0.f};

    const bf16x8* a0p = (const bf16x8*)&afrag_lds[0][0];
    const bf16x8* a1p = (const bf16x8*)&afrag_lds[1][0];
    const bf16x8* wfp = (const bf16x8*)wf + t0 * 64 + lane;

#pragma unroll 4
    for (int kc = 0; kc < 16; kc++) {
        int gidx = (kc & 1) ? g_o : g_e;
        bf16x8 a0 = a0p[kc * 64 + gidx];
        bf16x8 a1 = a1p[kc * 64 + gidx];
        bf16x8 b0 = wfp[kc * 512];
        bf16x8 b1 = wfp[kc * 512 + 64];
        acc00 = __builtin_amdgcn_mfma_f32_16x16x32_bf16(a0, b0, acc00, 0, 0, 0);
        acc01 = __builtin_amdgcn_mfma_f32_16x16x32_bf16(a0, b1, acc01, 0, 0, 0);
        acc10 = __builtin_amdgcn_mfma_f32_16x16x32_bf16(a1, b0, acc10, 0, 0, 0);
        acc11 = __builtin_amdgcn_mfma_f32_16x16x32_bf16(a1, b1, acc11, 0, 0, 0);
    }

    const int q = lane >> 4;
    const int c = lane & 15;
#pragma unroll
    for (int reg = 0; reg < 4; reg++) {
        int r0 = row0 + q * 4 + reg;
        if (r0 < N_NODES) {
            unsigned short* xr = x + (size_t)r0 * NHID;
            xr[t0 * 16 + c]       = f2bf(acc00[reg]);
            xr[(t0 + 1) * 16 + c] = f2bf(acc01[reg]);
        }
        int r1 = row0 + 16 + q * 4 + reg;
        if (r1 < N_NODES) {
            unsigned short* xr = x + (size_t)r1 * NHID;
            xr[t0 * 16 + c]       = f2bf(acc10[reg]);
            xr[(t0 + 1) * 16 + c] = f2bf(acc11[reg]);
        }
    }
}

// ---------------- scan phase A: block-local exclusive scan + out_norm ----------------
__global__ __launch_bounds__(1024) void scan_local(
    const int* __restrict__ in_deg, int* __restrict__ row_ptr, int* __restrict__ bsum,
    const int* __restrict__ out_deg, float* __restrict__ out_norm)
{
    __shared__ int wsum[16];
    const int tid = threadIdx.x;
    const int lane = tid & 63, wave = tid >> 6;
    int i = blockIdx.x * 1024 + tid;
    int v = (i < N_NODES) ? in_deg[i] : 0;
    int sv = v;
#pragma unroll
    for (int off = 1; off < 64; off <<= 1) {
        int t = __shfl_up(sv, off);
        if (lane >= off) sv += t;
    }
    if (lane == 63) wsum[wave] = sv;
    if (i < N_NODES)
        out_norm[i] = rsqrtf(fmaxf((float)out_deg[i], 1.0f));
    __syncthreads();
    if (wave == 0) {
        int wv = (lane < 16) ? wsum[lane] : 0;
#pragma unroll
        for (int off = 1; off < 16; off <<= 1) {
            int t = __shfl_up(wv, off);
            if (lane >= off) wv += t;
        }
        if (lane < 16) wsum[lane] = wv;
    }
    __syncthreads();
    int excl = ((wave > 0) ? wsum[wave - 1] : 0) + (sv - v);
    if (i < N_NODES) row_ptr[i] = excl;
    if (tid == 1023) bsum[blockIdx.x] = wsum[15];
}

// ---------------- scan phase B+C merged: each block re-scans bsums itself ----------------
__global__ __launch_bounds__(1024) void scan_add2(
    int* __restrict__ row_ptr, const int* __restrict__ bsum)
{
    __shared__ int off_s, tot_s;
    const int tid = threadIdx.x;
    if (tid < 64) {
        int v = (tid < NB_SCAN) ? bsum[tid] : 0;
        int sv = v;
#pragma unroll
        for (int off = 1; off < 64; off <<= 1) {
            int t = __shfl_up(sv, off);
            if (tid >= off) sv += t;
        }
        int pre = __shfl(sv, (blockIdx.x == 0) ? 0 : (blockIdx.x - 1));
        int tot = __shfl(sv, NB_SCAN - 1);
        if (tid == 0) {
            off_s = (blockIdx.x == 0) ? 0 : pre;
            tot_s = tot;
        }
    }
    __syncthreads();
    int i = blockIdx.x * 1024 + tid;
    if (i < N_NODES) row_ptr[i] += off_s;
    if (blockIdx.x == 0 && tid == 0) row_ptr[N_NODES] = tot_s;
}

// ---------------- CSR fill (atomic-free) ----------------
__global__ __launch_bounds__(256) void fill_kernel(
    const int* __restrict__ src, const int* __restrict__ dst,
    const int* __restrict__ row_ptr, const int* __restrict__ edge_pos,
    int* __restrict__ csr_src)
{
    int e = blockIdx.x * 256 + threadIdx.x;
    if (e < N_EDGES) {
        int d = dst[e];
        csr_src[row_ptr[d] + edge_pos[e]] = src[e];
    }
}

// ---------------- fused aggregate + norms + bias + LayerNorm ----------------
// one wave per node; half-waves process alternating edges; lane covers 4 feats (bf16).
__global__ __launch_bounds__(256) void aggregate_kernel(
    const unsigned short* __restrict__ x, const int* __restrict__ row_ptr,
    const int* __restrict__ csr_src, const float* __restrict__ out_norm,
    const float* __restrict__ b, const float* __restrict__ gamma,
    const float* __restrict__ beta, float* __restrict__ out)
{
    const int n    = blockIdx.x * 4 + (threadIdx.x >> 6);
    const int lane = threadIdx.x & 63;
    const int half = lane >> 5;
    const int c    = lane & 31;          // feat group: 4c..4c+3
    const int start = row_ptr[n];
    const int end   = row_ptr[n + 1];

    float a0 = 0.f, a1 = 0.f, a2 = 0.f, a3 = 0.f;

    for (int base = start; base < end; base += 64) {
        int me   = base + lane;
        int msrc = (me < end) ? csr_src[me] : 0;
        int cnt  = min(64, end - base);
        int npair = (cnt + 1) >> 1;
        int j = 0;
        for (; j + 4 <= npair; j += 4) {
            int i0 = 2 * j + half, i1 = i0 + 2, i2 = i0 + 4, i3 = i0 + 6;
            int s0 = __shfl(msrc, i0);
            int s1 = __shfl(msrc, i1);
            int s2 = __shfl(msrc, i2);
            int s3 = __shfl(msrc, i3);
            float w0 = (i0 < cnt) ? out_norm[s0] : 0.f;
            float w1 = (i1 < cnt) ? out_norm[s1] : 0.f;
            float w2 = (i2 < cnt) ? out_norm[s2] : 0.f;
            float w3 = (i3 < cnt) ? out_norm[s3] : 0.f;
            uint2 u0 = *(const uint2*)(x + (size_t)s0 * NHID + c * 4);
            uint2 u1 = *(const uint2*)(x + (size_t)s1 * NHID + c * 4);
            uint2 u2 = *(const uint2*)(x + (size_t)s2 * NHID + c * 4);
            uint2 u3 = *(const uint2*)(x + (size_t)s3 * NHID + c * 4);
            float p0, p1, p2, p3;
            bf2x(u0.x, p0, p1); bf2x(u0.y, p2, p3);
            a0 += p0 * w0; a1 += p1 * w0; a2 += p2 * w0; a3 += p3 * w0;
            bf2x(u1.x, p0, p1); bf2x(u1.y, p2, p3);
            a0 += p0 * w1; a1 += p1 * w1; a2 += p2 * w1; a3 += p3 * w1;
            bf2x(u2.x, p0, p1); bf2x(u2.y, p2, p3);
            a0 += p0 * w2; a1 += p1 * w2; a2 += p2 * w2; a3 += p3 * w2;
            bf2x(u3.x, p0, p1); bf2x(u3.y, p2, p3);
            a0 += p0 * w3; a1 += p1 * w3; a2 += p2 * w3; a3 += p3 * w3;
        }
        for (; j < npair; ++j) {
            int i0 = 2 * j + half;
            int s0 = __shfl(msrc, i0);
            float w0 = (i0 < cnt) ? out_norm[s0] : 0.f;
            uint2 u0 = *(const uint2*)(x + (size_t)s0 * NHID + c * 4);
            float p0, p1, p2, p3;
            bf2x(u0.x, p0, p1); bf2x(u0.y, p2, p3);
            a0 += p0 * w0; a1 += p1 * w0; a2 += p2 * w0; a3 += p3 * w0;
        }
    }

    // combine halves
    a0 += __shfl_xor(a0, 32);
    a1 += __shfl_xor(a1, 32);
    a2 += __shfl_xor(a2, 32);
    a3 += __shfl_xor(a3, 32);

    float inorm = rsqrtf(fmaxf((float)(end - start), 1.0f));
    float4 bb = *(const float4*)(b + c * 4);
    float v0 = a0 * inorm + bb.x;
    float v1 = a1 * inorm + bb.y;
    float v2 = a2 * inorm + bb.z;
    float v3 = a3 * inorm + bb.w;

    float s = v0 + v1 + v2 + v3;
#pragma unroll
    for (int off = 16; off > 0; off >>= 1) s += __shfl_xor(s, off);
    float mu = s * (1.0f / 128.0f);

    float d0 = v0 - mu, d1 = v1 - mu, d2 = v2 - mu, d3 = v3 - mu;
    float qd = d0 * d0 + d1 * d1 + d2 * d2 + d3 * d3;
#pragma unroll
    for (int off = 16; off > 0; off >>= 1) qd += __shfl_xor(qd, off);
    float var = qd * (1.0f / 128.0f);
    float rs = rsqrtf(var + LN_EPS);

    if (half == 0) {
        float4 gg = *(const float4*)(gamma + c * 4);
        float4 be = *(const float4*)(beta + c * 4);
        float4 o;
        o.x = d0 * rs * gg.x + be.x;
        o.y = d1 * rs * gg.y + be.y;
        o.z = d2 * rs * gg.z + be.z;
        o.w = d3 * rs * gg.w + be.w;
        *(float4*)(out + (size_t)n * NHID + c * 4) = o;
    }
}

// ---------------- launch ----------------
extern "C" void kernel_launch(void* const* d_in, const int* in_sizes, int n_in,
                              void* d_out, int out_size, void* d_ws, size_t ws_size,
                              hipStream_t stream) {
    const float* h     = (const float*)d_in[0];
    const int*   src   = (const int*)d_in[1];
    const int*   dst   = (const int*)d_in[2];
    const float* W     = (const float*)d_in[3];
    const float* b     = (const float*)d_in[4];
    const float* gamma = (const float*)d_in[5];
    const float* beta  = (const float*)d_in[6];
    float* out = (float*)d_out;

    char* ws = (char*)d_ws;
    const size_t DEG_BYTES = 200704;   // 50000*4 padded
    const size_t RP_BYTES  = 200960;   // 50001*4 padded
    int*            out_deg  = (int*)(ws);
    int*            in_deg   = (int*)(ws + DEG_BYTES);
    int*            row_ptr  = (int*)(ws + 2 * DEG_BYTES);
    float*          out_norm = (float*)(ws + 2 * DEG_BYTES + RP_BYTES);
    int*            bsum     = (int*)(ws + 3 * DEG_BYTES + RP_BYTES);
    int*            edge_pos = (int*)(ws + 3 * DEG_BYTES + RP_BYTES + 1024);
    int*            csr_src  = (int*)(ws + 3 * DEG_BYTES + RP_BYTES + 1024 + (size_t)N_EDGES * 4);
    unsigned short* wf       = (unsigned short*)(ws + 3 * DEG_BYTES + RP_BYTES + 1024 + 2 * (size_t)N_EDGES * 4);
    unsigned short* x        = (unsigned short*)(ws + 3 * DEG_BYTES + RP_BYTES + 1024 + 2 * (size_t)N_EDGES * 4 + 131072);

    prep_kernel<<<64, 256, 0, stream>>>(W, wf, (int4*)ws);
    fused_gemm_degree<<<GEMM_BLOCKS + DEG_BLOCKS, 256, 0, stream>>>(
        h, wf, x, src, dst, out_deg, in_deg, edge_pos);
    scan_local<<<NB_SCAN, 1024, 0, stream>>>(in_deg, row_ptr, bsum, out_deg, out_norm);
    scan_add2 <<<NB_SCAN, 1024, 0, stream>>>(row_ptr, bsum);
    fill_kernel<<<(N_EDGES + 255) / 256, 256, 0, stream>>>(src, dst, row_ptr, edge_pos, csr_src);
    aggregate_kernel<<<N_NODES / 4, 256, 0, stream>>>(
        x, row_ptr, csr_src, out_norm, b, gamma, beta, out);
}